// Round 15
// baseline (303.732 us; speedup 1.0000x reference)
//
#include <hip/hip_runtime.h>

// ---------------------------------------------------------------------------
// BEV encoder: bucketed points->BEV (LDS-aggregated) + 3x conv-BN-ReLU
// v12 = r12 verbatim (best: 288.5us) + ICB 8->16 for conv2/conv3 (halves
// barrier count; identical ic accumulation order -> bitwise same output).
// Bucket = r12's simple version (r13 LDS-staging and r14 write-coalescing
// both measured slower). Conv inner loop untouched (r6/7/9/11 lessons).
// ---------------------------------------------------------------------------

constexpr int BEVW = 250;
constexpr int SZC  = BEVW * BEVW;     // 62500 cells
constexpr int NB   = 512;             // blocks in bucket pass
constexpr int PPT  = 16;              // points/thread/chunk
constexpr int CHUNK = 256 * PPT;      // 4096
constexpr int NBKT = 100;             // 10x10 tiles of 25x25 cells
constexpr int NCELL = 625;            // cells per bucket
constexpr int CAPB = 43008;           // records capacity per bucket
constexpr int NSL  = 8;               // bnstats slices per channel

__device__ __forceinline__ unsigned f2ord(float f) {
    unsigned u = __float_as_uint(f);
    return (u & 0x80000000u) ? ~u : (u | 0x80000000u);
}
__device__ __forceinline__ float ord2f(unsigned u) {
    unsigned b = (u & 0x80000000u) ? (u & 0x7FFFFFFFu) : ~u;
    return __uint_as_float(b);
}

// ---- zero bucket counters ------------------------------------------------
__global__ void k_initg(unsigned* __restrict__ gcnt) {
    if (threadIdx.x < 128) gcnt[threadIdx.x] = 0u;
}

// ---- pass B: bin points into bucket record arrays (r12 verbatim) ---------
// rec = z_ord(32) | cell_local(10) | inten_q22(22)
__launch_bounds__(256)
__global__ void k_bucket(const float4* __restrict__ pts, int n,
                         unsigned long long* __restrict__ recs,
                         unsigned* __restrict__ gcnt) {
    __shared__ unsigned lcnt[NBKT];
    __shared__ unsigned lbase[NBKT];
    const int tid = threadIdx.x;
    if (tid < NBKT) lcnt[tid] = 0u;
    __syncthreads();

    const int ppb = (n + NB - 1) / NB;
    const int start = blockIdx.x * ppb;
    const int end = min(start + ppb, n);

    for (int c0 = start; c0 < end; c0 += CHUNK) {
        unsigned long long rec[PPT];
        int bkt[PPT];
        unsigned slot[PPT];
        unsigned vmask = 0u;
#pragma unroll
        for (int k = 0; k < PPT; ++k) {
            int p = c0 + k * 256 + tid;
            if (p >= end) continue;
            float4 q = pts[p];
            if (!(q.x >= -50.0f && q.x < 50.0f && q.y >= -50.0f && q.y < 50.0f))
                continue;
            // must match JAX/np f32 semantics: f32 add, f32 div, trunc, clip
            int xi = (int)((q.x + 50.0f) / 0.4f);
            int yi = (int)((q.y + 50.0f) / 0.4f);
            xi = min(max(xi, 0), BEVW - 1);
            yi = min(max(yi, 0), BEVW - 1);
            int b  = (yi / 25) * 10 + (xi / 25);
            int cl = (yi % 25) * 25 + (xi % 25);
            unsigned iq = (unsigned)(q.w * 4194304.0f);   // 2^22, q.w in [0,1)
            rec[k] = ((unsigned long long)f2ord(q.z) << 32) |
                     ((unsigned long long)(unsigned)cl << 22) | iq;
            bkt[k] = b;
            slot[k] = atomicAdd(&lcnt[b], 1u);
            vmask |= 1u << k;
        }
        __syncthreads();
        if (tid < NBKT) {
            unsigned c = lcnt[tid];
            if (c) lbase[tid] = atomicAdd(&gcnt[tid], c);
            lcnt[tid] = 0u;
        }
        __syncthreads();
#pragma unroll
        for (int k = 0; k < PPT; ++k) {
            if (!((vmask >> k) & 1u)) continue;
            unsigned idx = lbase[bkt[k]] + slot[k];
            if (idx < (unsigned)CAPB)
                recs[(size_t)bkt[k] * CAPB + idx] = rec[k];
        }
    }
}

// ---- pass C: per-bucket LDS reduction + fused finalize -------------------
__launch_bounds__(1024)
__global__ void k_reduce(const unsigned long long* __restrict__ recs,
                         const unsigned* __restrict__ gcnt,
                         float* __restrict__ bev) {
    __shared__ unsigned mxA[NCELL], mnA[NCELL], ctA[NCELL], siA[NCELL];
    const int b = blockIdx.x;
    for (int i = threadIdx.x; i < NCELL; i += 1024) {
        mxA[i] = 0u; mnA[i] = 0xFFFFFFFFu; ctA[i] = 0u; siA[i] = 0u;
    }
    __syncthreads();
    const unsigned nb = min(gcnt[b], (unsigned)CAPB);
    const unsigned long long* rb = recs + (size_t)b * CAPB;
    for (unsigned i = threadIdx.x; i < nb; i += 1024) {
        unsigned long long r = rb[i];
        unsigned zo = (unsigned)(r >> 32);
        unsigned cl = ((unsigned)(r >> 22)) & 0x3FFu;
        unsigned iq = (unsigned)r & 0x3FFFFFu;
        atomicMax(&mxA[cl], zo);
        atomicMin(&mnA[cl], zo);
        atomicAdd(&ctA[cl], 1u);
        atomicAdd(&siA[cl], iq);
    }
    __syncthreads();
    const int tx = b % 10, ty = b / 10;
    for (int i = threadIdx.x; i < NCELL; i += 1024) {
        int cy = ty * 25 + i / 25, cx = tx * 25 + i % 25;
        int cell = cy * BEVW + cx;
        unsigned c = ctA[i];
        bool has = c > 0u;
        float dn = (float)c;
        float isum = (float)siA[i] * (1.0f / 4194304.0f);
        bev[0 * SZC + cell] = has ? ord2f(mxA[i]) : 0.0f;
        bev[1 * SZC + cell] = has ? ord2f(mnA[i]) : 0.0f;
        bev[2 * SZC + cell] = log1pf(dn);
        bev[3 * SZC + cell] = has ? isum / dn : 0.0f;
    }
}

// ---- weight transpose: w[oc][ic][3][3] -> wt[ic][k][oc] ------------------
__global__ void k_wt(const float* __restrict__ w, float* __restrict__ wt,
                     int CIN, int COUT) {
    int i = blockIdx.x * blockDim.x + threadIdx.x;
    if (i >= COUT * CIN * 9) return;
    int oc = i / (CIN * 9);
    int r  = i % (CIN * 9);
    int ic = r / 9, k = r % 9;
    wt[(ic * 9 + k) * COUT + oc] = w[i];
}

// ---- conv 3x3 SAME, 16x16 tile, 1 px/thread, SGPR weights ----------------
// in: [CIN][250][250] raw prev conv out; staging applies relu(A*x+B) if FUSE
// (A,B = ab[2c],ab[2c+1]); OOB stays 0. wt: [CIN][9][COUT]. out: conv+bias.
template <int CIN, int COUT, int ICB, int OCG, bool FUSE>
__launch_bounds__(256)
__global__ void k_conv(const float* __restrict__ in, const float* __restrict__ wt,
                       const float* __restrict__ bias, const float* __restrict__ ab,
                       float* __restrict__ out) {
    __shared__ float s_in[ICB][18 * 18];

    const int tid = threadIdx.x;
    const int u = tid & 15, v = tid >> 4;
    const int tile = blockIdx.x;              // 0..255
    const int tx = (tile & 15) * 16, ty = (tile >> 4) * 16;
    const int oc0 = blockIdx.y * OCG;

    float acc[OCG];
#pragma unroll
    for (int o = 0; o < OCG; ++o) acc[o] = 0.0f;

    for (int ic0 = 0; ic0 < CIN; ic0 += ICB) {
        __syncthreads();
        // stage input tile with halo; fused prev-layer BN+ReLU (in-bounds only)
        for (int e = tid; e < ICB * 324; e += 256) {
            int c = e / 324, rem = e % 324;
            int r = rem / 18, q = rem % 18;
            int cg = ic0 + c;
            int gy = ty - 1 + r, gx = tx - 1 + q;
            float x = 0.0f;
            if (gy >= 0 && gy < BEVW && gx >= 0 && gx < BEVW) {
                x = in[(size_t)cg * SZC + gy * BEVW + gx];
                if (FUSE) x = fmaxf(fmaf(x, ab[2 * cg], ab[2 * cg + 1]), 0.0f);
            }
            s_in[c][rem] = x;
        }
        __syncthreads();

#pragma unroll
        for (int icl = 0; icl < ICB; ++icl) {
            const int icg = ic0 + icl;
#pragma unroll
            for (int tap = 0; tap < 9; ++tap) {
                const int ky = tap / 3, kx = tap % 3;
                float x = s_in[icl][(v + ky) * 18 + u + kx];
                // block-uniform address -> scalar loads into SGPRs
                const float* wk = wt + ((size_t)(icg * 9 + tap) * COUT + oc0);
#pragma unroll
                for (int o = 0; o < OCG; ++o)
                    acc[o] = fmaf(x, wk[o], acc[o]);
            }
        }
    }

    const int ox = tx + u, oy = ty + v;
    if (ox < BEVW && oy < BEVW) {
#pragma unroll
        for (int o = 0; o < OCG; ++o)
            out[(size_t)(oc0 + o) * SZC + oy * BEVW + ox] = acc[o] + bias[oc0 + o];
    }
}

// ---- BN stats stage 1: per (channel, slice) f64 partials -----------------
__global__ void k_bnstats1(const float* __restrict__ y, double* __restrict__ part) {
    const int c = blockIdx.x, s = blockIdx.y;
    const int lo = s * ((SZC + NSL - 1) / NSL);
    const int hi = min(lo + (SZC + NSL - 1) / NSL, SZC);
    const float* p = y + (size_t)c * SZC;
    double sm = 0.0, s2 = 0.0;
    for (int i = lo + threadIdx.x; i < hi; i += 256) {
        float v = p[i];
        sm += (double)v;
        s2 += (double)v * (double)v;
    }
    for (int off = 32; off; off >>= 1) {
        sm += __shfl_down(sm, off);
        s2 += __shfl_down(s2, off);
    }
    __shared__ double sh[8];
    int wid = threadIdx.x >> 6;
    if ((threadIdx.x & 63) == 0) { sh[wid * 2] = sm; sh[wid * 2 + 1] = s2; }
    __syncthreads();
    if (threadIdx.x == 0) {
        double S = 0.0, S2 = 0.0;
        for (int wv = 0; wv < 4; ++wv) { S += sh[wv * 2]; S2 += sh[wv * 2 + 1]; }
        part[(c * NSL + s) * 2]     = S;
        part[(c * NSL + s) * 2 + 1] = S2;
    }
}

// ---- BN stats stage 2: fold -> (A,B) affine; BN+ReLU = relu(A*x+B) -------
__global__ void k_bnstats2(const double* __restrict__ part, const float* __restrict__ g,
                           const float* __restrict__ beta, float* __restrict__ statsAB) {
    int c = threadIdx.x;
    double S = 0.0, S2 = 0.0;
    for (int s = 0; s < NSL; ++s) {
        S  += part[(c * NSL + s) * 2];
        S2 += part[(c * NSL + s) * 2 + 1];
    }
    double mu  = S / (double)SZC;
    double var = S2 / (double)SZC - mu * mu;
    double A = (1.0 / sqrt(var + 1e-5)) * (double)g[c];
    statsAB[2 * c]     = (float)A;
    statsAB[2 * c + 1] = (float)((double)beta[c] - mu * A);
}

// ---- final BN apply + ReLU ----------------------------------------------
__global__ void k_bnreluS(const float* __restrict__ y, const float* __restrict__ ab,
                          float* __restrict__ out) {
    int c = blockIdx.y;
    int i = blockIdx.x * blockDim.x + threadIdx.x;
    if (i >= SZC) return;
    size_t idx = (size_t)c * SZC + i;
    out[idx] = fmaxf(fmaf(y[idx], ab[2 * c], ab[2 * c + 1]), 0.0f);
}

// ---------------------------------------------------------------------------
extern "C" void kernel_launch(void* const* d_in, const int* in_sizes, int n_in,
                              void* d_out, int out_size, void* d_ws, size_t ws_size,
                              hipStream_t stream) {
    const float4* pts = (const float4*)d_in[0];
    const float* w1 = (const float*)d_in[1];
    const float* b1 = (const float*)d_in[2];
    const float* g1 = (const float*)d_in[3];
    const float* be1 = (const float*)d_in[4];
    const float* w2 = (const float*)d_in[5];
    const float* b2 = (const float*)d_in[6];
    const float* g2 = (const float*)d_in[7];
    const float* be2 = (const float*)d_in[8];
    const float* w3 = (const float*)d_in[9];
    const float* b3 = (const float*)d_in[10];
    const float* g3 = (const float*)d_in[11];
    const float* be3 = (const float*)d_in[12];

    float* ws = (float*)d_ws;
    const size_t wsf = ws_size / 4;

    // --- fixed tail at end of workspace ---
    constexpr size_t TAILF = 128 + 250000 + 64 + 128 + 128 + 2048 + 1152 + 18432 + 36864;
    float* tail = ws + (wsf - TAILF);
    unsigned* gcnt = (unsigned*)tail;
    float* bev = tail + 128;                  // 4*SZC
    float* st1 = bev + 4 * SZC;               // 64  (A,B per ch)
    float* st2 = st1 + 64;                    // 128
    float* st3 = st2 + 128;                   // 128
    double* part = (double*)(st3 + 128);      // 64*NSL*2 doubles = 2048 floats
    float* wt1 = st3 + 128 + 2048;            // 1152
    float* wt2 = wt1 + 1152;                  // 18432
    float* wt3 = wt2 + 18432;                 // 36864

    // --- dynamic region: recs, then activations alias (recs dead) ---
    unsigned long long* recs = (unsigned long long*)ws;   // 8,601,600 floats
    float* y1 = ws;                                       // 32*SZC
    float* y2 = ws + 2000000;                             // 64*SZC
    float* out = (float*)d_out;

    int n = in_sizes[0] / 4;                              // 5,000,000 points
    const int cellBlocks = (SZC + 255) / 256;

    // weight transposes
    k_wt<<<(32 * 4 * 9 + 255) / 256, 256, 0, stream>>>(w1, wt1, 4, 32);
    k_wt<<<(64 * 32 * 9 + 255) / 256, 256, 0, stream>>>(w2, wt2, 32, 64);
    k_wt<<<(64 * 64 * 9 + 255) / 256, 256, 0, stream>>>(w3, wt3, 64, 64);

    // points -> BEV
    k_initg<<<1, 128, 0, stream>>>(gcnt);
    k_bucket<<<NB, 256, 0, stream>>>(pts, n, recs, gcnt);
    k_reduce<<<NBKT, 1024, 0, stream>>>(recs, gcnt, bev);

    // layer 1: 4 -> 32 (raw conv out; BN1+ReLU consumed by conv2 staging)
    k_conv<4, 32, 4, 16, false><<<dim3(256, 2), 256, 0, stream>>>(bev, wt1, b1, nullptr, y1);
    k_bnstats1<<<dim3(32, NSL), 256, 0, stream>>>(y1, part);
    k_bnstats2<<<1, 32, 0, stream>>>(part, g1, be1, st1);

    // layer 2: 32 -> 64 (BN1+ReLU fused into staging; ICB=16 -> 2 phases)
    k_conv<32, 64, 16, 16, true><<<dim3(256, 4), 256, 0, stream>>>(y1, wt2, b2, st1, y2);
    k_bnstats1<<<dim3(64, NSL), 256, 0, stream>>>(y2, part);
    k_bnstats2<<<1, 64, 0, stream>>>(part, g2, be2, st2);

    // layer 3: 64 -> 64 (BN2+ReLU fused into staging; ICB=16 -> 4 phases)
    k_conv<64, 64, 16, 16, true><<<dim3(256, 4), 256, 0, stream>>>(y2, wt3, b3, st2, out);
    k_bnstats1<<<dim3(64, NSL), 256, 0, stream>>>(out, part);
    k_bnstats2<<<1, 64, 0, stream>>>(part, g3, be3, st3);

    // final BN3 + ReLU in place
    k_bnreluS<<<dim3(cellBlocks, 64), 256, 0, stream>>>(out, st3, out);
}

// Round 16
// 292.307 us; speedup vs baseline: 1.0391x; 1.0391x over previous
//
#include <hip/hip_runtime.h>

// ---------------------------------------------------------------------------
// BEV encoder: bucketed points->BEV (LDS-aggregated) + 3x conv-BN-ReLU
// v13 = r12 verbatim (champion: 288.5us) with ONE isolated change:
// bucket NB 512 -> 1024 (4 blocks/CU for latency hiding; logic unchanged).
// Conv = r12/r5 exact (9 variants tried, all worse). Bucket structure = r12
// exact (r13 LDS-staging and r14 coalescing both slower).
// ---------------------------------------------------------------------------

constexpr int BEVW = 250;
constexpr int SZC  = BEVW * BEVW;     // 62500 cells
constexpr int NB   = 1024;            // blocks in bucket pass (4/CU)
constexpr int PPT  = 16;              // points/thread/chunk
constexpr int CHUNK = 256 * PPT;      // 4096
constexpr int NBKT = 100;             // 10x10 tiles of 25x25 cells
constexpr int NCELL = 625;            // cells per bucket
constexpr int CAPB = 43008;           // records capacity per bucket
constexpr int NSL  = 8;               // bnstats slices per channel

__device__ __forceinline__ unsigned f2ord(float f) {
    unsigned u = __float_as_uint(f);
    return (u & 0x80000000u) ? ~u : (u | 0x80000000u);
}
__device__ __forceinline__ float ord2f(unsigned u) {
    unsigned b = (u & 0x80000000u) ? (u & 0x7FFFFFFFu) : ~u;
    return __uint_as_float(b);
}

// ---- zero bucket counters ------------------------------------------------
__global__ void k_initg(unsigned* __restrict__ gcnt) {
    if (threadIdx.x < 128) gcnt[threadIdx.x] = 0u;
}

// ---- pass B: bin points into bucket record arrays (r12 verbatim) ---------
// rec = z_ord(32) | cell_local(10) | inten_q22(22)
__launch_bounds__(256)
__global__ void k_bucket(const float4* __restrict__ pts, int n,
                         unsigned long long* __restrict__ recs,
                         unsigned* __restrict__ gcnt) {
    __shared__ unsigned lcnt[NBKT];
    __shared__ unsigned lbase[NBKT];
    const int tid = threadIdx.x;
    if (tid < NBKT) lcnt[tid] = 0u;
    __syncthreads();

    const int ppb = (n + NB - 1) / NB;
    const int start = blockIdx.x * ppb;
    const int end = min(start + ppb, n);

    for (int c0 = start; c0 < end; c0 += CHUNK) {
        unsigned long long rec[PPT];
        int bkt[PPT];
        unsigned slot[PPT];
        unsigned vmask = 0u;
#pragma unroll
        for (int k = 0; k < PPT; ++k) {
            int p = c0 + k * 256 + tid;
            if (p >= end) continue;
            float4 q = pts[p];
            if (!(q.x >= -50.0f && q.x < 50.0f && q.y >= -50.0f && q.y < 50.0f))
                continue;
            // must match JAX/np f32 semantics: f32 add, f32 div, trunc, clip
            int xi = (int)((q.x + 50.0f) / 0.4f);
            int yi = (int)((q.y + 50.0f) / 0.4f);
            xi = min(max(xi, 0), BEVW - 1);
            yi = min(max(yi, 0), BEVW - 1);
            int b  = (yi / 25) * 10 + (xi / 25);
            int cl = (yi % 25) * 25 + (xi % 25);
            unsigned iq = (unsigned)(q.w * 4194304.0f);   // 2^22, q.w in [0,1)
            rec[k] = ((unsigned long long)f2ord(q.z) << 32) |
                     ((unsigned long long)(unsigned)cl << 22) | iq;
            bkt[k] = b;
            slot[k] = atomicAdd(&lcnt[b], 1u);
            vmask |= 1u << k;
        }
        __syncthreads();
        if (tid < NBKT) {
            unsigned c = lcnt[tid];
            if (c) lbase[tid] = atomicAdd(&gcnt[tid], c);
            lcnt[tid] = 0u;
        }
        __syncthreads();
#pragma unroll
        for (int k = 0; k < PPT; ++k) {
            if (!((vmask >> k) & 1u)) continue;
            unsigned idx = lbase[bkt[k]] + slot[k];
            if (idx < (unsigned)CAPB)
                recs[(size_t)bkt[k] * CAPB + idx] = rec[k];
        }
    }
}

// ---- pass C: per-bucket LDS reduction + fused finalize -------------------
__launch_bounds__(1024)
__global__ void k_reduce(const unsigned long long* __restrict__ recs,
                         const unsigned* __restrict__ gcnt,
                         float* __restrict__ bev) {
    __shared__ unsigned mxA[NCELL], mnA[NCELL], ctA[NCELL], siA[NCELL];
    const int b = blockIdx.x;
    for (int i = threadIdx.x; i < NCELL; i += 1024) {
        mxA[i] = 0u; mnA[i] = 0xFFFFFFFFu; ctA[i] = 0u; siA[i] = 0u;
    }
    __syncthreads();
    const unsigned nb = min(gcnt[b], (unsigned)CAPB);
    const unsigned long long* rb = recs + (size_t)b * CAPB;
    for (unsigned i = threadIdx.x; i < nb; i += 1024) {
        unsigned long long r = rb[i];
        unsigned zo = (unsigned)(r >> 32);
        unsigned cl = ((unsigned)(r >> 22)) & 0x3FFu;
        unsigned iq = (unsigned)r & 0x3FFFFFu;
        atomicMax(&mxA[cl], zo);
        atomicMin(&mnA[cl], zo);
        atomicAdd(&ctA[cl], 1u);
        atomicAdd(&siA[cl], iq);
    }
    __syncthreads();
    const int tx = b % 10, ty = b / 10;
    for (int i = threadIdx.x; i < NCELL; i += 1024) {
        int cy = ty * 25 + i / 25, cx = tx * 25 + i % 25;
        int cell = cy * BEVW + cx;
        unsigned c = ctA[i];
        bool has = c > 0u;
        float dn = (float)c;
        float isum = (float)siA[i] * (1.0f / 4194304.0f);
        bev[0 * SZC + cell] = has ? ord2f(mxA[i]) : 0.0f;
        bev[1 * SZC + cell] = has ? ord2f(mnA[i]) : 0.0f;
        bev[2 * SZC + cell] = log1pf(dn);
        bev[3 * SZC + cell] = has ? isum / dn : 0.0f;
    }
}

// ---- weight transpose: w[oc][ic][3][3] -> wt[ic][k][oc] ------------------
__global__ void k_wt(const float* __restrict__ w, float* __restrict__ wt,
                     int CIN, int COUT) {
    int i = blockIdx.x * blockDim.x + threadIdx.x;
    if (i >= COUT * CIN * 9) return;
    int oc = i / (CIN * 9);
    int r  = i % (CIN * 9);
    int ic = r / 9, k = r % 9;
    wt[(ic * 9 + k) * COUT + oc] = w[i];
}

// ---- conv 3x3 SAME, 16x16 tile, 1 px/thread, SGPR weights (r5 verbatim) --
// in: [CIN][250][250] raw prev conv out; staging applies relu(A*x+B) if FUSE
// (A,B = ab[2c],ab[2c+1]); OOB stays 0. wt: [CIN][9][COUT]. out: conv+bias.
template <int CIN, int COUT, int ICB, int OCG, bool FUSE>
__launch_bounds__(256)
__global__ void k_conv(const float* __restrict__ in, const float* __restrict__ wt,
                       const float* __restrict__ bias, const float* __restrict__ ab,
                       float* __restrict__ out) {
    __shared__ float s_in[ICB][18 * 18];

    const int tid = threadIdx.x;
    const int u = tid & 15, v = tid >> 4;
    const int tile = blockIdx.x;              // 0..255
    const int tx = (tile & 15) * 16, ty = (tile >> 4) * 16;
    const int oc0 = blockIdx.y * OCG;

    float acc[OCG];
#pragma unroll
    for (int o = 0; o < OCG; ++o) acc[o] = 0.0f;

    for (int ic0 = 0; ic0 < CIN; ic0 += ICB) {
        __syncthreads();
        // stage input tile with halo; fused prev-layer BN+ReLU (in-bounds only)
        for (int e = tid; e < ICB * 324; e += 256) {
            int c = e / 324, rem = e % 324;
            int r = rem / 18, q = rem % 18;
            int cg = ic0 + c;
            int gy = ty - 1 + r, gx = tx - 1 + q;
            float x = 0.0f;
            if (gy >= 0 && gy < BEVW && gx >= 0 && gx < BEVW) {
                x = in[(size_t)cg * SZC + gy * BEVW + gx];
                if (FUSE) x = fmaxf(fmaf(x, ab[2 * cg], ab[2 * cg + 1]), 0.0f);
            }
            s_in[c][rem] = x;
        }
        __syncthreads();

#pragma unroll
        for (int icl = 0; icl < ICB; ++icl) {
            const int icg = ic0 + icl;
#pragma unroll
            for (int tap = 0; tap < 9; ++tap) {
                const int ky = tap / 3, kx = tap % 3;
                float x = s_in[icl][(v + ky) * 18 + u + kx];
                // block-uniform address -> scalar loads into SGPRs
                const float* wk = wt + ((size_t)(icg * 9 + tap) * COUT + oc0);
#pragma unroll
                for (int o = 0; o < OCG; ++o)
                    acc[o] = fmaf(x, wk[o], acc[o]);
            }
        }
    }

    const int ox = tx + u, oy = ty + v;
    if (ox < BEVW && oy < BEVW) {
#pragma unroll
        for (int o = 0; o < OCG; ++o)
            out[(size_t)(oc0 + o) * SZC + oy * BEVW + ox] = acc[o] + bias[oc0 + o];
    }
}

// ---- BN stats stage 1: per (channel, slice) f64 partials -----------------
__global__ void k_bnstats1(const float* __restrict__ y, double* __restrict__ part) {
    const int c = blockIdx.x, s = blockIdx.y;
    const int lo = s * ((SZC + NSL - 1) / NSL);
    const int hi = min(lo + (SZC + NSL - 1) / NSL, SZC);
    const float* p = y + (size_t)c * SZC;
    double sm = 0.0, s2 = 0.0;
    for (int i = lo + threadIdx.x; i < hi; i += 256) {
        float v = p[i];
        sm += (double)v;
        s2 += (double)v * (double)v;
    }
    for (int off = 32; off; off >>= 1) {
        sm += __shfl_down(sm, off);
        s2 += __shfl_down(s2, off);
    }
    __shared__ double sh[8];
    int wid = threadIdx.x >> 6;
    if ((threadIdx.x & 63) == 0) { sh[wid * 2] = sm; sh[wid * 2 + 1] = s2; }
    __syncthreads();
    if (threadIdx.x == 0) {
        double S = 0.0, S2 = 0.0;
        for (int wv = 0; wv < 4; ++wv) { S += sh[wv * 2]; S2 += sh[wv * 2 + 1]; }
        part[(c * NSL + s) * 2]     = S;
        part[(c * NSL + s) * 2 + 1] = S2;
    }
}

// ---- BN stats stage 2: fold -> (A,B) affine; BN+ReLU = relu(A*x+B) -------
__global__ void k_bnstats2(const double* __restrict__ part, const float* __restrict__ g,
                           const float* __restrict__ beta, float* __restrict__ statsAB) {
    int c = threadIdx.x;
    double S = 0.0, S2 = 0.0;
    for (int s = 0; s < NSL; ++s) {
        S  += part[(c * NSL + s) * 2];
        S2 += part[(c * NSL + s) * 2 + 1];
    }
    double mu  = S / (double)SZC;
    double var = S2 / (double)SZC - mu * mu;
    double A = (1.0 / sqrt(var + 1e-5)) * (double)g[c];
    statsAB[2 * c]     = (float)A;
    statsAB[2 * c + 1] = (float)((double)beta[c] - mu * A);
}

// ---- final BN apply + ReLU ----------------------------------------------
__global__ void k_bnreluS(const float* __restrict__ y, const float* __restrict__ ab,
                          float* __restrict__ out) {
    int c = blockIdx.y;
    int i = blockIdx.x * blockDim.x + threadIdx.x;
    if (i >= SZC) return;
    size_t idx = (size_t)c * SZC + i;
    out[idx] = fmaxf(fmaf(y[idx], ab[2 * c], ab[2 * c + 1]), 0.0f);
}

// ---------------------------------------------------------------------------
extern "C" void kernel_launch(void* const* d_in, const int* in_sizes, int n_in,
                              void* d_out, int out_size, void* d_ws, size_t ws_size,
                              hipStream_t stream) {
    const float4* pts = (const float4*)d_in[0];
    const float* w1 = (const float*)d_in[1];
    const float* b1 = (const float*)d_in[2];
    const float* g1 = (const float*)d_in[3];
    const float* be1 = (const float*)d_in[4];
    const float* w2 = (const float*)d_in[5];
    const float* b2 = (const float*)d_in[6];
    const float* g2 = (const float*)d_in[7];
    const float* be2 = (const float*)d_in[8];
    const float* w3 = (const float*)d_in[9];
    const float* b3 = (const float*)d_in[10];
    const float* g3 = (const float*)d_in[11];
    const float* be3 = (const float*)d_in[12];

    float* ws = (float*)d_ws;
    const size_t wsf = ws_size / 4;

    // --- fixed tail at end of workspace ---
    constexpr size_t TAILF = 128 + 250000 + 64 + 128 + 128 + 2048 + 1152 + 18432 + 36864;
    float* tail = ws + (wsf - TAILF);
    unsigned* gcnt = (unsigned*)tail;
    float* bev = tail + 128;                  // 4*SZC
    float* st1 = bev + 4 * SZC;               // 64  (A,B per ch)
    float* st2 = st1 + 64;                    // 128
    float* st3 = st2 + 128;                   // 128
    double* part = (double*)(st3 + 128);      // 64*NSL*2 doubles = 2048 floats
    float* wt1 = st3 + 128 + 2048;            // 1152
    float* wt2 = wt1 + 1152;                  // 18432
    float* wt3 = wt2 + 18432;                 // 36864

    // --- dynamic region: recs, then activations alias (recs dead) ---
    unsigned long long* recs = (unsigned long long*)ws;   // 8,601,600 floats
    float* y1 = ws;                                       // 32*SZC
    float* y2 = ws + 2000000;                             // 64*SZC
    float* out = (float*)d_out;

    int n = in_sizes[0] / 4;                              // 5,000,000 points
    const int cellBlocks = (SZC + 255) / 256;

    // weight transposes
    k_wt<<<(32 * 4 * 9 + 255) / 256, 256, 0, stream>>>(w1, wt1, 4, 32);
    k_wt<<<(64 * 32 * 9 + 255) / 256, 256, 0, stream>>>(w2, wt2, 32, 64);
    k_wt<<<(64 * 64 * 9 + 255) / 256, 256, 0, stream>>>(w3, wt3, 64, 64);

    // points -> BEV
    k_initg<<<1, 128, 0, stream>>>(gcnt);
    k_bucket<<<NB, 256, 0, stream>>>(pts, n, recs, gcnt);
    k_reduce<<<NBKT, 1024, 0, stream>>>(recs, gcnt, bev);

    // layer 1: 4 -> 32 (raw conv out; BN1+ReLU consumed by conv2 staging)
    k_conv<4, 32, 4, 16, false><<<dim3(256, 2), 256, 0, stream>>>(bev, wt1, b1, nullptr, y1);
    k_bnstats1<<<dim3(32, NSL), 256, 0, stream>>>(y1, part);
    k_bnstats2<<<1, 32, 0, stream>>>(part, g1, be1, st1);

    // layer 2: 32 -> 64 (BN1+ReLU fused into staging)
    k_conv<32, 64, 8, 16, true><<<dim3(256, 4), 256, 0, stream>>>(y1, wt2, b2, st1, y2);
    k_bnstats1<<<dim3(64, NSL), 256, 0, stream>>>(y2, part);
    k_bnstats2<<<1, 64, 0, stream>>>(part, g2, be2, st2);

    // layer 3: 64 -> 64 (BN2+ReLU fused into staging; raw out -> d_out)
    k_conv<64, 64, 8, 16, true><<<dim3(256, 4), 256, 0, stream>>>(y2, wt3, b3, st2, out);
    k_bnstats1<<<dim3(64, NSL), 256, 0, stream>>>(out, part);
    k_bnstats2<<<1, 64, 0, stream>>>(part, g3, be3, st3);

    // final BN3 + ReLU in place
    k_bnreluS<<<dim3(cellBlocks, 64), 256, 0, stream>>>(out, st3, out);
}

// Round 17
// 284.639 us; speedup vs baseline: 1.0671x; 1.0269x over previous
//
#include <hip/hip_runtime.h>

// ---------------------------------------------------------------------------
// BEV encoder: bucketed points->BEV (LDS-aggregated) + 3x conv-BN-ReLU
// v14 = r12 exact (champion: 288.5us) + 4-way split k_reduce (100 -> 400
// blocks; per-bucket record quarters folded to global partials, merged in
// fixed order -> bit-identical). Gated on ws_size; falls back to r12 reduce.
// Conv & bucket untouched (10 conv / 3 bucket variants all lost to this).
// ---------------------------------------------------------------------------

constexpr int BEVW = 250;
constexpr int SZC  = BEVW * BEVW;     // 62500 cells
constexpr int NB   = 512;             // blocks in bucket pass
constexpr int PPT  = 16;              // points/thread/chunk
constexpr int CHUNK = 256 * PPT;      // 4096
constexpr int NBKT = 100;             // 10x10 tiles of 25x25 cells
constexpr int NCELL = 625;            // cells per bucket
constexpr int CAPB = 43008;           // records capacity per bucket
constexpr int NSL  = 8;               // bnstats slices per channel
constexpr int NSPL = 4;               // reduce split factor

__device__ __forceinline__ unsigned f2ord(float f) {
    unsigned u = __float_as_uint(f);
    return (u & 0x80000000u) ? ~u : (u | 0x80000000u);
}
__device__ __forceinline__ float ord2f(unsigned u) {
    unsigned b = (u & 0x80000000u) ? (u & 0x7FFFFFFFu) : ~u;
    return __uint_as_float(b);
}

// ---- zero bucket counters ------------------------------------------------
__global__ void k_initg(unsigned* __restrict__ gcnt) {
    if (threadIdx.x < 128) gcnt[threadIdx.x] = 0u;
}

// ---- pass B: bin points into bucket record arrays (r12 verbatim) ---------
// rec = z_ord(32) | cell_local(10) | inten_q22(22)
__launch_bounds__(256)
__global__ void k_bucket(const float4* __restrict__ pts, int n,
                         unsigned long long* __restrict__ recs,
                         unsigned* __restrict__ gcnt) {
    __shared__ unsigned lcnt[NBKT];
    __shared__ unsigned lbase[NBKT];
    const int tid = threadIdx.x;
    if (tid < NBKT) lcnt[tid] = 0u;
    __syncthreads();

    const int ppb = (n + NB - 1) / NB;
    const int start = blockIdx.x * ppb;
    const int end = min(start + ppb, n);

    for (int c0 = start; c0 < end; c0 += CHUNK) {
        unsigned long long rec[PPT];
        int bkt[PPT];
        unsigned slot[PPT];
        unsigned vmask = 0u;
#pragma unroll
        for (int k = 0; k < PPT; ++k) {
            int p = c0 + k * 256 + tid;
            if (p >= end) continue;
            float4 q = pts[p];
            if (!(q.x >= -50.0f && q.x < 50.0f && q.y >= -50.0f && q.y < 50.0f))
                continue;
            // must match JAX/np f32 semantics: f32 add, f32 div, trunc, clip
            int xi = (int)((q.x + 50.0f) / 0.4f);
            int yi = (int)((q.y + 50.0f) / 0.4f);
            xi = min(max(xi, 0), BEVW - 1);
            yi = min(max(yi, 0), BEVW - 1);
            int b  = (yi / 25) * 10 + (xi / 25);
            int cl = (yi % 25) * 25 + (xi % 25);
            unsigned iq = (unsigned)(q.w * 4194304.0f);   // 2^22, q.w in [0,1)
            rec[k] = ((unsigned long long)f2ord(q.z) << 32) |
                     ((unsigned long long)(unsigned)cl << 22) | iq;
            bkt[k] = b;
            slot[k] = atomicAdd(&lcnt[b], 1u);
            vmask |= 1u << k;
        }
        __syncthreads();
        if (tid < NBKT) {
            unsigned c = lcnt[tid];
            if (c) lbase[tid] = atomicAdd(&gcnt[tid], c);
            lcnt[tid] = 0u;
        }
        __syncthreads();
#pragma unroll
        for (int k = 0; k < PPT; ++k) {
            if (!((vmask >> k) & 1u)) continue;
            unsigned idx = lbase[bkt[k]] + slot[k];
            if (idx < (unsigned)CAPB)
                recs[(size_t)bkt[k] * CAPB + idx] = rec[k];
        }
    }
}

// ---- pass C (fallback): per-bucket LDS reduction + fused finalize --------
__launch_bounds__(1024)
__global__ void k_reduce(const unsigned long long* __restrict__ recs,
                         const unsigned* __restrict__ gcnt,
                         float* __restrict__ bev) {
    __shared__ unsigned mxA[NCELL], mnA[NCELL], ctA[NCELL], siA[NCELL];
    const int b = blockIdx.x;
    for (int i = threadIdx.x; i < NCELL; i += 1024) {
        mxA[i] = 0u; mnA[i] = 0xFFFFFFFFu; ctA[i] = 0u; siA[i] = 0u;
    }
    __syncthreads();
    const unsigned nb = min(gcnt[b], (unsigned)CAPB);
    const unsigned long long* rb = recs + (size_t)b * CAPB;
    for (unsigned i = threadIdx.x; i < nb; i += 1024) {
        unsigned long long r = rb[i];
        unsigned zo = (unsigned)(r >> 32);
        unsigned cl = ((unsigned)(r >> 22)) & 0x3FFu;
        unsigned iq = (unsigned)r & 0x3FFFFFu;
        atomicMax(&mxA[cl], zo);
        atomicMin(&mnA[cl], zo);
        atomicAdd(&ctA[cl], 1u);
        atomicAdd(&siA[cl], iq);
    }
    __syncthreads();
    const int tx = b % 10, ty = b / 10;
    for (int i = threadIdx.x; i < NCELL; i += 1024) {
        int cy = ty * 25 + i / 25, cx = tx * 25 + i % 25;
        int cell = cy * BEVW + cx;
        unsigned c = ctA[i];
        bool has = c > 0u;
        float dn = (float)c;
        float isum = (float)siA[i] * (1.0f / 4194304.0f);
        bev[0 * SZC + cell] = has ? ord2f(mxA[i]) : 0.0f;
        bev[1 * SZC + cell] = has ? ord2f(mnA[i]) : 0.0f;
        bev[2 * SZC + cell] = log1pf(dn);
        bev[3 * SZC + cell] = has ? isum / dn : 0.0f;
    }
}

// ---- pass C (split): partial reduce over a quarter of a bucket -----------
// parts[(b*NSPL+s)*NCELL + i] = {max, min, count, isum} (uint4)
__launch_bounds__(1024)
__global__ void k_reduceP(const unsigned long long* __restrict__ recs,
                          const unsigned* __restrict__ gcnt,
                          uint4* __restrict__ parts) {
    __shared__ unsigned mxA[NCELL], mnA[NCELL], ctA[NCELL], siA[NCELL];
    const int b = blockIdx.x, s = blockIdx.y;
    for (int i = threadIdx.x; i < NCELL; i += 1024) {
        mxA[i] = 0u; mnA[i] = 0xFFFFFFFFu; ctA[i] = 0u; siA[i] = 0u;
    }
    __syncthreads();
    const unsigned nb = min(gcnt[b], (unsigned)CAPB);
    const unsigned lo = nb * (unsigned)s / NSPL;
    const unsigned hi = nb * (unsigned)(s + 1) / NSPL;
    const unsigned long long* rb = recs + (size_t)b * CAPB;
    for (unsigned i = lo + threadIdx.x; i < hi; i += 1024) {
        unsigned long long r = rb[i];
        unsigned zo = (unsigned)(r >> 32);
        unsigned cl = ((unsigned)(r >> 22)) & 0x3FFu;
        unsigned iq = (unsigned)r & 0x3FFFFFu;
        atomicMax(&mxA[cl], zo);
        atomicMin(&mnA[cl], zo);
        atomicAdd(&ctA[cl], 1u);
        atomicAdd(&siA[cl], iq);
    }
    __syncthreads();
    uint4* dst = parts + ((size_t)b * NSPL + s) * NCELL;
    for (int i = threadIdx.x; i < NCELL; i += 1024)
        dst[i] = make_uint4(mxA[i], mnA[i], ctA[i], siA[i]);
}

// ---- merge partials (fixed order) + finalize BEV -------------------------
__global__ void k_merge(const uint4* __restrict__ parts, float* __restrict__ bev) {
    int t = blockIdx.x * blockDim.x + threadIdx.x;
    if (t >= NBKT * NCELL) return;
    const int b = t / NCELL, i = t % NCELL;
    unsigned mx = 0u, mn = 0xFFFFFFFFu, ct = 0u, si = 0u;
#pragma unroll
    for (int s = 0; s < NSPL; ++s) {
        uint4 p = parts[((size_t)b * NSPL + s) * NCELL + i];
        mx = max(mx, p.x);
        mn = min(mn, p.y);
        ct += p.z;
        si += p.w;
    }
    const int tx = b % 10, ty = b / 10;
    int cy = ty * 25 + i / 25, cx = tx * 25 + i % 25;
    int cell = cy * BEVW + cx;
    bool has = ct > 0u;
    float dn = (float)ct;
    float isum = (float)si * (1.0f / 4194304.0f);
    bev[0 * SZC + cell] = has ? ord2f(mx) : 0.0f;
    bev[1 * SZC + cell] = has ? ord2f(mn) : 0.0f;
    bev[2 * SZC + cell] = log1pf(dn);
    bev[3 * SZC + cell] = has ? isum / dn : 0.0f;
}

// ---- weight transpose: w[oc][ic][3][3] -> wt[ic][k][oc] ------------------
__global__ void k_wt(const float* __restrict__ w, float* __restrict__ wt,
                     int CIN, int COUT) {
    int i = blockIdx.x * blockDim.x + threadIdx.x;
    if (i >= COUT * CIN * 9) return;
    int oc = i / (CIN * 9);
    int r  = i % (CIN * 9);
    int ic = r / 9, k = r % 9;
    wt[(ic * 9 + k) * COUT + oc] = w[i];
}

// ---- conv 3x3 SAME, 16x16 tile, 1 px/thread, SGPR weights (r5 verbatim) --
template <int CIN, int COUT, int ICB, int OCG, bool FUSE>
__launch_bounds__(256)
__global__ void k_conv(const float* __restrict__ in, const float* __restrict__ wt,
                       const float* __restrict__ bias, const float* __restrict__ ab,
                       float* __restrict__ out) {
    __shared__ float s_in[ICB][18 * 18];

    const int tid = threadIdx.x;
    const int u = tid & 15, v = tid >> 4;
    const int tile = blockIdx.x;              // 0..255
    const int tx = (tile & 15) * 16, ty = (tile >> 4) * 16;
    const int oc0 = blockIdx.y * OCG;

    float acc[OCG];
#pragma unroll
    for (int o = 0; o < OCG; ++o) acc[o] = 0.0f;

    for (int ic0 = 0; ic0 < CIN; ic0 += ICB) {
        __syncthreads();
        // stage input tile with halo; fused prev-layer BN+ReLU (in-bounds only)
        for (int e = tid; e < ICB * 324; e += 256) {
            int c = e / 324, rem = e % 324;
            int r = rem / 18, q = rem % 18;
            int cg = ic0 + c;
            int gy = ty - 1 + r, gx = tx - 1 + q;
            float x = 0.0f;
            if (gy >= 0 && gy < BEVW && gx >= 0 && gx < BEVW) {
                x = in[(size_t)cg * SZC + gy * BEVW + gx];
                if (FUSE) x = fmaxf(fmaf(x, ab[2 * cg], ab[2 * cg + 1]), 0.0f);
            }
            s_in[c][rem] = x;
        }
        __syncthreads();

#pragma unroll
        for (int icl = 0; icl < ICB; ++icl) {
            const int icg = ic0 + icl;
#pragma unroll
            for (int tap = 0; tap < 9; ++tap) {
                const int ky = tap / 3, kx = tap % 3;
                float x = s_in[icl][(v + ky) * 18 + u + kx];
                // block-uniform address -> scalar loads into SGPRs
                const float* wk = wt + ((size_t)(icg * 9 + tap) * COUT + oc0);
#pragma unroll
                for (int o = 0; o < OCG; ++o)
                    acc[o] = fmaf(x, wk[o], acc[o]);
            }
        }
    }

    const int ox = tx + u, oy = ty + v;
    if (ox < BEVW && oy < BEVW) {
#pragma unroll
        for (int o = 0; o < OCG; ++o)
            out[(size_t)(oc0 + o) * SZC + oy * BEVW + ox] = acc[o] + bias[oc0 + o];
    }
}

// ---- BN stats stage 1: per (channel, slice) f64 partials -----------------
__global__ void k_bnstats1(const float* __restrict__ y, double* __restrict__ part) {
    const int c = blockIdx.x, s = blockIdx.y;
    const int lo = s * ((SZC + NSL - 1) / NSL);
    const int hi = min(lo + (SZC + NSL - 1) / NSL, SZC);
    const float* p = y + (size_t)c * SZC;
    double sm = 0.0, s2 = 0.0;
    for (int i = lo + threadIdx.x; i < hi; i += 256) {
        float v = p[i];
        sm += (double)v;
        s2 += (double)v * (double)v;
    }
    for (int off = 32; off; off >>= 1) {
        sm += __shfl_down(sm, off);
        s2 += __shfl_down(s2, off);
    }
    __shared__ double sh[8];
    int wid = threadIdx.x >> 6;
    if ((threadIdx.x & 63) == 0) { sh[wid * 2] = sm; sh[wid * 2 + 1] = s2; }
    __syncthreads();
    if (threadIdx.x == 0) {
        double S = 0.0, S2 = 0.0;
        for (int wv = 0; wv < 4; ++wv) { S += sh[wv * 2]; S2 += sh[wv * 2 + 1]; }
        part[(c * NSL + s) * 2]     = S;
        part[(c * NSL + s) * 2 + 1] = S2;
    }
}

// ---- BN stats stage 2: fold -> (A,B) affine; BN+ReLU = relu(A*x+B) -------
__global__ void k_bnstats2(const double* __restrict__ part, const float* __restrict__ g,
                           const float* __restrict__ beta, float* __restrict__ statsAB) {
    int c = threadIdx.x;
    double S = 0.0, S2 = 0.0;
    for (int s = 0; s < NSL; ++s) {
        S  += part[(c * NSL + s) * 2];
        S2 += part[(c * NSL + s) * 2 + 1];
    }
    double mu  = S / (double)SZC;
    double var = S2 / (double)SZC - mu * mu;
    double A = (1.0 / sqrt(var + 1e-5)) * (double)g[c];
    statsAB[2 * c]     = (float)A;
    statsAB[2 * c + 1] = (float)((double)beta[c] - mu * A);
}

// ---- final BN apply + ReLU ----------------------------------------------
__global__ void k_bnreluS(const float* __restrict__ y, const float* __restrict__ ab,
                          float* __restrict__ out) {
    int c = blockIdx.y;
    int i = blockIdx.x * blockDim.x + threadIdx.x;
    if (i >= SZC) return;
    size_t idx = (size_t)c * SZC + i;
    out[idx] = fmaxf(fmaf(y[idx], ab[2 * c], ab[2 * c + 1]), 0.0f);
}

// ---------------------------------------------------------------------------
extern "C" void kernel_launch(void* const* d_in, const int* in_sizes, int n_in,
                              void* d_out, int out_size, void* d_ws, size_t ws_size,
                              hipStream_t stream) {
    const float4* pts = (const float4*)d_in[0];
    const float* w1 = (const float*)d_in[1];
    const float* b1 = (const float*)d_in[2];
    const float* g1 = (const float*)d_in[3];
    const float* be1 = (const float*)d_in[4];
    const float* w2 = (const float*)d_in[5];
    const float* b2 = (const float*)d_in[6];
    const float* g2 = (const float*)d_in[7];
    const float* be2 = (const float*)d_in[8];
    const float* w3 = (const float*)d_in[9];
    const float* b3 = (const float*)d_in[10];
    const float* g3 = (const float*)d_in[11];
    const float* be3 = (const float*)d_in[12];

    float* ws = (float*)d_ws;
    const size_t wsf = ws_size / 4;

    // --- fixed tail at end of workspace ---
    constexpr size_t TAILF = 128 + 250000 + 64 + 128 + 128 + 2048 + 1152 + 18432 + 36864;
    float* tail = ws + (wsf - TAILF);
    unsigned* gcnt = (unsigned*)tail;
    float* bev = tail + 128;                  // 4*SZC
    float* st1 = bev + 4 * SZC;               // 64  (A,B per ch)
    float* st2 = st1 + 64;                    // 128
    float* st3 = st2 + 128;                   // 128
    double* part = (double*)(st3 + 128);      // 64*NSL*2 doubles = 2048 floats
    float* wt1 = st3 + 128 + 2048;            // 1152
    float* wt2 = wt1 + 1152;                  // 18432
    float* wt3 = wt2 + 18432;                 // 36864

    // --- dynamic region: recs, then activations alias (recs dead) ---
    unsigned long long* recs = (unsigned long long*)ws;   // 8,601,600 floats
    constexpr size_t RECS_F = (size_t)NBKT * CAPB * 2;    // 8,601,600
    float* y1 = ws;                                       // 32*SZC
    float* y2 = ws + 2000000;                             // 64*SZC
    float* out = (float*)d_out;

    // split-reduce partials: 100*4*625 uint4 = 1,000,000 floats, after recs
    constexpr size_t PARTS_F = (size_t)NBKT * NSPL * NCELL * 4;
    const bool splitR = wsf >= RECS_F + PARTS_F + TAILF + 1024;
    uint4* partsR = (uint4*)(ws + RECS_F);

    int n = in_sizes[0] / 4;                              // 5,000,000 points
    const int cellBlocks = (SZC + 255) / 256;

    // weight transposes
    k_wt<<<(32 * 4 * 9 + 255) / 256, 256, 0, stream>>>(w1, wt1, 4, 32);
    k_wt<<<(64 * 32 * 9 + 255) / 256, 256, 0, stream>>>(w2, wt2, 32, 64);
    k_wt<<<(64 * 64 * 9 + 255) / 256, 256, 0, stream>>>(w3, wt3, 64, 64);

    // points -> BEV
    k_initg<<<1, 128, 0, stream>>>(gcnt);
    k_bucket<<<NB, 256, 0, stream>>>(pts, n, recs, gcnt);
    if (splitR) {
        k_reduceP<<<dim3(NBKT, NSPL), 1024, 0, stream>>>(recs, gcnt, partsR);
        k_merge<<<(NBKT * NCELL + 255) / 256, 256, 0, stream>>>(partsR, bev);
    } else {
        k_reduce<<<NBKT, 1024, 0, stream>>>(recs, gcnt, bev);
    }

    // layer 1: 4 -> 32 (raw conv out; BN1+ReLU consumed by conv2 staging)
    k_conv<4, 32, 4, 16, false><<<dim3(256, 2), 256, 0, stream>>>(bev, wt1, b1, nullptr, y1);
    k_bnstats1<<<dim3(32, NSL), 256, 0, stream>>>(y1, part);
    k_bnstats2<<<1, 32, 0, stream>>>(part, g1, be1, st1);

    // layer 2: 32 -> 64 (BN1+ReLU fused into staging)
    k_conv<32, 64, 8, 16, true><<<dim3(256, 4), 256, 0, stream>>>(y1, wt2, b2, st1, y2);
    k_bnstats1<<<dim3(64, NSL), 256, 0, stream>>>(y2, part);
    k_bnstats2<<<1, 64, 0, stream>>>(part, g2, be2, st2);

    // layer 3: 64 -> 64 (BN2+ReLU fused into staging; raw out -> d_out)
    k_conv<64, 64, 8, 16, true><<<dim3(256, 4), 256, 0, stream>>>(y2, wt3, b3, st2, out);
    k_bnstats1<<<dim3(64, NSL), 256, 0, stream>>>(out, part);
    k_bnstats2<<<1, 64, 0, stream>>>(part, g3, be3, st3);

    // final BN3 + ReLU in place
    k_bnreluS<<<dim3(cellBlocks, 64), 256, 0, stream>>>(out, st3, out);
}

// Round 18
// 283.636 us; speedup vs baseline: 1.0709x; 1.0035x over previous
//
#include <hip/hip_runtime.h>

// ---------------------------------------------------------------------------
// BEV encoder: bucketed points->BEV (LDS-aggregated) + 3x conv-BN-ReLU
// v15 = r17 (champion: 284.6us) + two value-preserving conv micro-opts:
//  (a) LDS row stride 24 (+1 col shift): wave's four v-group read offsets
//      {0,24,16,8} mod 32 -> perfect 2-way banks (free per m136), vs old
//      stride-18 {0,18,4,22} 3-way collisions (4.7M conflict cycles).
//  (b) interior tiles (196/256): bounds-check-free staging, middle 16 cols
//      as aligned float2 pairs (halves staging load instructions).
// Same values, same FMA order -> bitwise-identical output.
// Bucket/reduce/BN = r17 exact (split reduce kept: it won ~4us).
// ---------------------------------------------------------------------------

constexpr int BEVW = 250;
constexpr int SZC  = BEVW * BEVW;     // 62500 cells
constexpr int NB   = 512;             // blocks in bucket pass
constexpr int PPT  = 16;              // points/thread/chunk
constexpr int CHUNK = 256 * PPT;      // 4096
constexpr int NBKT = 100;             // 10x10 tiles of 25x25 cells
constexpr int NCELL = 625;            // cells per bucket
constexpr int CAPB = 43008;           // records capacity per bucket
constexpr int NSL  = 8;               // bnstats slices per channel
constexpr int NSPL = 4;               // reduce split factor

__device__ __forceinline__ unsigned f2ord(float f) {
    unsigned u = __float_as_uint(f);
    return (u & 0x80000000u) ? ~u : (u | 0x80000000u);
}
__device__ __forceinline__ float ord2f(unsigned u) {
    unsigned b = (u & 0x80000000u) ? (u & 0x7FFFFFFFu) : ~u;
    return __uint_as_float(b);
}

// ---- zero bucket counters ------------------------------------------------
__global__ void k_initg(unsigned* __restrict__ gcnt) {
    if (threadIdx.x < 128) gcnt[threadIdx.x] = 0u;
}

// ---- pass B: bin points into bucket record arrays (r12 verbatim) ---------
// rec = z_ord(32) | cell_local(10) | inten_q22(22)
__launch_bounds__(256)
__global__ void k_bucket(const float4* __restrict__ pts, int n,
                         unsigned long long* __restrict__ recs,
                         unsigned* __restrict__ gcnt) {
    __shared__ unsigned lcnt[NBKT];
    __shared__ unsigned lbase[NBKT];
    const int tid = threadIdx.x;
    if (tid < NBKT) lcnt[tid] = 0u;
    __syncthreads();

    const int ppb = (n + NB - 1) / NB;
    const int start = blockIdx.x * ppb;
    const int end = min(start + ppb, n);

    for (int c0 = start; c0 < end; c0 += CHUNK) {
        unsigned long long rec[PPT];
        int bkt[PPT];
        unsigned slot[PPT];
        unsigned vmask = 0u;
#pragma unroll
        for (int k = 0; k < PPT; ++k) {
            int p = c0 + k * 256 + tid;
            if (p >= end) continue;
            float4 q = pts[p];
            if (!(q.x >= -50.0f && q.x < 50.0f && q.y >= -50.0f && q.y < 50.0f))
                continue;
            // must match JAX/np f32 semantics: f32 add, f32 div, trunc, clip
            int xi = (int)((q.x + 50.0f) / 0.4f);
            int yi = (int)((q.y + 50.0f) / 0.4f);
            xi = min(max(xi, 0), BEVW - 1);
            yi = min(max(yi, 0), BEVW - 1);
            int b  = (yi / 25) * 10 + (xi / 25);
            int cl = (yi % 25) * 25 + (xi % 25);
            unsigned iq = (unsigned)(q.w * 4194304.0f);   // 2^22, q.w in [0,1)
            rec[k] = ((unsigned long long)f2ord(q.z) << 32) |
                     ((unsigned long long)(unsigned)cl << 22) | iq;
            bkt[k] = b;
            slot[k] = atomicAdd(&lcnt[b], 1u);
            vmask |= 1u << k;
        }
        __syncthreads();
        if (tid < NBKT) {
            unsigned c = lcnt[tid];
            if (c) lbase[tid] = atomicAdd(&gcnt[tid], c);
            lcnt[tid] = 0u;
        }
        __syncthreads();
#pragma unroll
        for (int k = 0; k < PPT; ++k) {
            if (!((vmask >> k) & 1u)) continue;
            unsigned idx = lbase[bkt[k]] + slot[k];
            if (idx < (unsigned)CAPB)
                recs[(size_t)bkt[k] * CAPB + idx] = rec[k];
        }
    }
}

// ---- pass C (fallback): per-bucket LDS reduction + fused finalize --------
__launch_bounds__(1024)
__global__ void k_reduce(const unsigned long long* __restrict__ recs,
                         const unsigned* __restrict__ gcnt,
                         float* __restrict__ bev) {
    __shared__ unsigned mxA[NCELL], mnA[NCELL], ctA[NCELL], siA[NCELL];
    const int b = blockIdx.x;
    for (int i = threadIdx.x; i < NCELL; i += 1024) {
        mxA[i] = 0u; mnA[i] = 0xFFFFFFFFu; ctA[i] = 0u; siA[i] = 0u;
    }
    __syncthreads();
    const unsigned nb = min(gcnt[b], (unsigned)CAPB);
    const unsigned long long* rb = recs + (size_t)b * CAPB;
    for (unsigned i = threadIdx.x; i < nb; i += 1024) {
        unsigned long long r = rb[i];
        unsigned zo = (unsigned)(r >> 32);
        unsigned cl = ((unsigned)(r >> 22)) & 0x3FFu;
        unsigned iq = (unsigned)r & 0x3FFFFFu;
        atomicMax(&mxA[cl], zo);
        atomicMin(&mnA[cl], zo);
        atomicAdd(&ctA[cl], 1u);
        atomicAdd(&siA[cl], iq);
    }
    __syncthreads();
    const int tx = b % 10, ty = b / 10;
    for (int i = threadIdx.x; i < NCELL; i += 1024) {
        int cy = ty * 25 + i / 25, cx = tx * 25 + i % 25;
        int cell = cy * BEVW + cx;
        unsigned c = ctA[i];
        bool has = c > 0u;
        float dn = (float)c;
        float isum = (float)siA[i] * (1.0f / 4194304.0f);
        bev[0 * SZC + cell] = has ? ord2f(mxA[i]) : 0.0f;
        bev[1 * SZC + cell] = has ? ord2f(mnA[i]) : 0.0f;
        bev[2 * SZC + cell] = log1pf(dn);
        bev[3 * SZC + cell] = has ? isum / dn : 0.0f;
    }
}

// ---- pass C (split): partial reduce over a quarter of a bucket -----------
__launch_bounds__(1024)
__global__ void k_reduceP(const unsigned long long* __restrict__ recs,
                          const unsigned* __restrict__ gcnt,
                          uint4* __restrict__ parts) {
    __shared__ unsigned mxA[NCELL], mnA[NCELL], ctA[NCELL], siA[NCELL];
    const int b = blockIdx.x, s = blockIdx.y;
    for (int i = threadIdx.x; i < NCELL; i += 1024) {
        mxA[i] = 0u; mnA[i] = 0xFFFFFFFFu; ctA[i] = 0u; siA[i] = 0u;
    }
    __syncthreads();
    const unsigned nb = min(gcnt[b], (unsigned)CAPB);
    const unsigned lo = nb * (unsigned)s / NSPL;
    const unsigned hi = nb * (unsigned)(s + 1) / NSPL;
    const unsigned long long* rb = recs + (size_t)b * CAPB;
    for (unsigned i = lo + threadIdx.x; i < hi; i += 1024) {
        unsigned long long r = rb[i];
        unsigned zo = (unsigned)(r >> 32);
        unsigned cl = ((unsigned)(r >> 22)) & 0x3FFu;
        unsigned iq = (unsigned)r & 0x3FFFFFu;
        atomicMax(&mxA[cl], zo);
        atomicMin(&mnA[cl], zo);
        atomicAdd(&ctA[cl], 1u);
        atomicAdd(&siA[cl], iq);
    }
    __syncthreads();
    uint4* dst = parts + ((size_t)b * NSPL + s) * NCELL;
    for (int i = threadIdx.x; i < NCELL; i += 1024)
        dst[i] = make_uint4(mxA[i], mnA[i], ctA[i], siA[i]);
}

// ---- merge partials (fixed order) + finalize BEV -------------------------
__global__ void k_merge(const uint4* __restrict__ parts, float* __restrict__ bev) {
    int t = blockIdx.x * blockDim.x + threadIdx.x;
    if (t >= NBKT * NCELL) return;
    const int b = t / NCELL, i = t % NCELL;
    unsigned mx = 0u, mn = 0xFFFFFFFFu, ct = 0u, si = 0u;
#pragma unroll
    for (int s = 0; s < NSPL; ++s) {
        uint4 p = parts[((size_t)b * NSPL + s) * NCELL + i];
        mx = max(mx, p.x);
        mn = min(mn, p.y);
        ct += p.z;
        si += p.w;
    }
    const int tx = b % 10, ty = b / 10;
    int cy = ty * 25 + i / 25, cx = tx * 25 + i % 25;
    int cell = cy * BEVW + cx;
    bool has = ct > 0u;
    float dn = (float)ct;
    float isum = (float)si * (1.0f / 4194304.0f);
    bev[0 * SZC + cell] = has ? ord2f(mx) : 0.0f;
    bev[1 * SZC + cell] = has ? ord2f(mn) : 0.0f;
    bev[2 * SZC + cell] = log1pf(dn);
    bev[3 * SZC + cell] = has ? isum / dn : 0.0f;
}

// ---- weight transpose: w[oc][ic][3][3] -> wt[ic][k][oc] ------------------
__global__ void k_wt(const float* __restrict__ w, float* __restrict__ wt,
                     int CIN, int COUT) {
    int i = blockIdx.x * blockDim.x + threadIdx.x;
    if (i >= COUT * CIN * 9) return;
    int oc = i / (CIN * 9);
    int r  = i % (CIN * 9);
    int ic = r / 9, k = r % 9;
    wt[(ic * 9 + k) * COUT + oc] = w[i];
}

// ---- conv 3x3 SAME, 16x16 tile, 1 px/thread, SGPR weights ----------------
// LDS row stride 24 (+1 col shift): perfect 2-way bank pattern on tap reads.
// Interior tiles: bounds-free staging, middle 16 cols as aligned float2.
// Same values, same FMA order as r17 -> bitwise-identical output.
template <int CIN, int COUT, int ICB, int OCG, bool FUSE>
__launch_bounds__(256)
__global__ void k_conv(const float* __restrict__ in, const float* __restrict__ wt,
                       const float* __restrict__ bias, const float* __restrict__ ab,
                       float* __restrict__ out) {
    constexpr int RS = 24;                    // padded row stride
    __shared__ float s_in[ICB][18 * RS];

    const int tid = threadIdx.x;
    const int u = tid & 15, v = tid >> 4;
    const int tile = blockIdx.x;              // 0..255
    const int tx = (tile & 15) * 16, ty = (tile >> 4) * 16;
    const int oc0 = blockIdx.y * OCG;
    const bool interior = (tx >= 16) && (tx <= 224) && (ty >= 16) && (ty <= 224);

    float acc[OCG];
#pragma unroll
    for (int o = 0; o < OCG; ++o) acc[o] = 0.0f;

    for (int ic0 = 0; ic0 < CIN; ic0 += ICB) {
        __syncthreads();
        if (interior) {
            // halo window fully in-bounds: no checks, vector middle columns
            const float* base = in + (size_t)ic0 * SZC + (ty - 1) * BEVW + (tx - 1);
            // pairs: columns 1..16 (8 aligned float2 per row)
            for (int e = tid; e < ICB * 144; e += 256) {
                int c = e / 144, rr = e % 144;
                int r = rr >> 3, pp = rr & 7;
                int q = 1 + 2 * pp;
                float2 x2 = *(const float2*)(base + (size_t)c * SZC + r * BEVW + q);
                if (FUSE) {
                    int cg = ic0 + c;
                    float A = ab[2 * cg], Bc = ab[2 * cg + 1];
                    x2.x = fmaxf(fmaf(x2.x, A, Bc), 0.0f);
                    x2.y = fmaxf(fmaf(x2.y, A, Bc), 0.0f);
                }
                *(float2*)&s_in[c][r * RS + q + 1] = x2;
            }
            // edges: columns 0 and 17
            for (int e = tid; e < ICB * 36; e += 256) {
                int c = e / 36, t = e % 36;
                int r = t >> 1, q = (t & 1) ? 17 : 0;
                float x = base[(size_t)c * SZC + r * BEVW + q];
                if (FUSE) {
                    int cg = ic0 + c;
                    x = fmaxf(fmaf(x, ab[2 * cg], ab[2 * cg + 1]), 0.0f);
                }
                s_in[c][r * RS + q + 1] = x;
            }
        } else {
            for (int e = tid; e < ICB * 324; e += 256) {
                int c = e / 324, rem = e % 324;
                int r = rem / 18, q = rem % 18;
                int cg = ic0 + c;
                int gy = ty - 1 + r, gx = tx - 1 + q;
                float x = 0.0f;
                if (gy >= 0 && gy < BEVW && gx >= 0 && gx < BEVW) {
                    x = in[(size_t)cg * SZC + gy * BEVW + gx];
                    if (FUSE) x = fmaxf(fmaf(x, ab[2 * cg], ab[2 * cg + 1]), 0.0f);
                }
                s_in[c][r * RS + q + 1] = x;
            }
        }
        __syncthreads();

#pragma unroll
        for (int icl = 0; icl < ICB; ++icl) {
            const int icg = ic0 + icl;
#pragma unroll
            for (int tap = 0; tap < 9; ++tap) {
                const int ky = tap / 3, kx = tap % 3;
                float x = s_in[icl][(v + ky) * RS + (u + kx) + 1];
                // block-uniform address -> scalar loads into SGPRs
                const float* wk = wt + ((size_t)(icg * 9 + tap) * COUT + oc0);
#pragma unroll
                for (int o = 0; o < OCG; ++o)
                    acc[o] = fmaf(x, wk[o], acc[o]);
            }
        }
    }

    const int ox = tx + u, oy = ty + v;
    if (ox < BEVW && oy < BEVW) {
#pragma unroll
        for (int o = 0; o < OCG; ++o)
            out[(size_t)(oc0 + o) * SZC + oy * BEVW + ox] = acc[o] + bias[oc0 + o];
    }
}

// ---- BN stats stage 1: per (channel, slice) f64 partials -----------------
__global__ void k_bnstats1(const float* __restrict__ y, double* __restrict__ part) {
    const int c = blockIdx.x, s = blockIdx.y;
    const int lo = s * ((SZC + NSL - 1) / NSL);
    const int hi = min(lo + (SZC + NSL - 1) / NSL, SZC);
    const float* p = y + (size_t)c * SZC;
    double sm = 0.0, s2 = 0.0;
    for (int i = lo + threadIdx.x; i < hi; i += 256) {
        float v = p[i];
        sm += (double)v;
        s2 += (double)v * (double)v;
    }
    for (int off = 32; off; off >>= 1) {
        sm += __shfl_down(sm, off);
        s2 += __shfl_down(s2, off);
    }
    __shared__ double sh[8];
    int wid = threadIdx.x >> 6;
    if ((threadIdx.x & 63) == 0) { sh[wid * 2] = sm; sh[wid * 2 + 1] = s2; }
    __syncthreads();
    if (threadIdx.x == 0) {
        double S = 0.0, S2 = 0.0;
        for (int wv = 0; wv < 4; ++wv) { S += sh[wv * 2]; S2 += sh[wv * 2 + 1]; }
        part[(c * NSL + s) * 2]     = S;
        part[(c * NSL + s) * 2 + 1] = S2;
    }
}

// ---- BN stats stage 2: fold -> (A,B) affine; BN+ReLU = relu(A*x+B) -------
__global__ void k_bnstats2(const double* __restrict__ part, const float* __restrict__ g,
                           const float* __restrict__ beta, float* __restrict__ statsAB) {
    int c = threadIdx.x;
    double S = 0.0, S2 = 0.0;
    for (int s = 0; s < NSL; ++s) {
        S  += part[(c * NSL + s) * 2];
        S2 += part[(c * NSL + s) * 2 + 1];
    }
    double mu  = S / (double)SZC;
    double var = S2 / (double)SZC - mu * mu;
    double A = (1.0 / sqrt(var + 1e-5)) * (double)g[c];
    statsAB[2 * c]     = (float)A;
    statsAB[2 * c + 1] = (float)((double)beta[c] - mu * A);
}

// ---- final BN apply + ReLU ----------------------------------------------
__global__ void k_bnreluS(const float* __restrict__ y, const float* __restrict__ ab,
                          float* __restrict__ out) {
    int c = blockIdx.y;
    int i = blockIdx.x * blockDim.x + threadIdx.x;
    if (i >= SZC) return;
    size_t idx = (size_t)c * SZC + i;
    out[idx] = fmaxf(fmaf(y[idx], ab[2 * c], ab[2 * c + 1]), 0.0f);
}

// ---------------------------------------------------------------------------
extern "C" void kernel_launch(void* const* d_in, const int* in_sizes, int n_in,
                              void* d_out, int out_size, void* d_ws, size_t ws_size,
                              hipStream_t stream) {
    const float4* pts = (const float4*)d_in[0];
    const float* w1 = (const float*)d_in[1];
    const float* b1 = (const float*)d_in[2];
    const float* g1 = (const float*)d_in[3];
    const float* be1 = (const float*)d_in[4];
    const float* w2 = (const float*)d_in[5];
    const float* b2 = (const float*)d_in[6];
    const float* g2 = (const float*)d_in[7];
    const float* be2 = (const float*)d_in[8];
    const float* w3 = (const float*)d_in[9];
    const float* b3 = (const float*)d_in[10];
    const float* g3 = (const float*)d_in[11];
    const float* be3 = (const float*)d_in[12];

    float* ws = (float*)d_ws;
    const size_t wsf = ws_size / 4;

    // --- fixed tail at end of workspace ---
    constexpr size_t TAILF = 128 + 250000 + 64 + 128 + 128 + 2048 + 1152 + 18432 + 36864;
    float* tail = ws + (wsf - TAILF);
    unsigned* gcnt = (unsigned*)tail;
    float* bev = tail + 128;                  // 4*SZC
    float* st1 = bev + 4 * SZC;               // 64  (A,B per ch)
    float* st2 = st1 + 64;                    // 128
    float* st3 = st2 + 128;                   // 128
    double* part = (double*)(st3 + 128);      // 64*NSL*2 doubles = 2048 floats
    float* wt1 = st3 + 128 + 2048;            // 1152
    float* wt2 = wt1 + 1152;                  // 18432
    float* wt3 = wt2 + 18432;                 // 36864

    // --- dynamic region: recs, then activations alias (recs dead) ---
    unsigned long long* recs = (unsigned long long*)ws;   // 8,601,600 floats
    constexpr size_t RECS_F = (size_t)NBKT * CAPB * 2;    // 8,601,600
    float* y1 = ws;                                       // 32*SZC
    float* y2 = ws + 2000000;                             // 64*SZC
    float* out = (float*)d_out;

    // split-reduce partials: 100*4*625 uint4 = 1,000,000 floats, after recs
    constexpr size_t PARTS_F = (size_t)NBKT * NSPL * NCELL * 4;
    const bool splitR = wsf >= RECS_F + PARTS_F + TAILF + 1024;
    uint4* partsR = (uint4*)(ws + RECS_F);

    int n = in_sizes[0] / 4;                              // 5,000,000 points
    const int cellBlocks = (SZC + 255) / 256;

    // weight transposes
    k_wt<<<(32 * 4 * 9 + 255) / 256, 256, 0, stream>>>(w1, wt1, 4, 32);
    k_wt<<<(64 * 32 * 9 + 255) / 256, 256, 0, stream>>>(w2, wt2, 32, 64);
    k_wt<<<(64 * 64 * 9 + 255) / 256, 256, 0, stream>>>(w3, wt3, 64, 64);

    // points -> BEV
    k_initg<<<1, 128, 0, stream>>>(gcnt);
    k_bucket<<<NB, 256, 0, stream>>>(pts, n, recs, gcnt);
    if (splitR) {
        k_reduceP<<<dim3(NBKT, NSPL), 1024, 0, stream>>>(recs, gcnt, partsR);
        k_merge<<<(NBKT * NCELL + 255) / 256, 256, 0, stream>>>(partsR, bev);
    } else {
        k_reduce<<<NBKT, 1024, 0, stream>>>(recs, gcnt, bev);
    }

    // layer 1: 4 -> 32 (raw conv out; BN1+ReLU consumed by conv2 staging)
    k_conv<4, 32, 4, 16, false><<<dim3(256, 2), 256, 0, stream>>>(bev, wt1, b1, nullptr, y1);
    k_bnstats1<<<dim3(32, NSL), 256, 0, stream>>>(y1, part);
    k_bnstats2<<<1, 32, 0, stream>>>(part, g1, be1, st1);

    // layer 2: 32 -> 64 (BN1+ReLU fused into staging)
    k_conv<32, 64, 8, 16, true><<<dim3(256, 4), 256, 0, stream>>>(y1, wt2, b2, st1, y2);
    k_bnstats1<<<dim3(64, NSL), 256, 0, stream>>>(y2, part);
    k_bnstats2<<<1, 64, 0, stream>>>(part, g2, be2, st2);

    // layer 3: 64 -> 64 (BN2+ReLU fused into staging; raw out -> d_out)
    k_conv<64, 64, 8, 16, true><<<dim3(256, 4), 256, 0, stream>>>(y2, wt3, b3, st2, out);
    k_bnstats1<<<dim3(64, NSL), 256, 0, stream>>>(out, part);
    k_bnstats2<<<1, 64, 0, stream>>>(part, g3, be3, st3);

    // final BN3 + ReLU in place
    k_bnreluS<<<dim3(cellBlocks, 64), 256, 0, stream>>>(out, st3, out);
}

// Round 19
// 277.096 us; speedup vs baseline: 1.0961x; 1.0236x over previous
//
#include <hip/hip_runtime.h>

// ---------------------------------------------------------------------------
// BEV encoder: bucketed points->BEV (LDS-aggregated) + 3x conv-BN-ReLU
// v16 = r18 (283.6us) with launch-chain slimming (17 -> 11 dispatches):
//  - k_prep merges gcnt-zero + 3 weight transposes
//  - bnstats2 eliminated: conv2/conv3 fold f64 BN partials into LDS sAB at
//    block start (fixed-order f64 fold, bitwise-identical across blocks);
//    k_bnreluS folds its own channel. Stream order makes part reuse safe.
// Kernel internals = r18 exact (converged after 12 structural experiments).
// ---------------------------------------------------------------------------

constexpr int BEVW = 250;
constexpr int SZC  = BEVW * BEVW;     // 62500 cells
constexpr int NB   = 512;             // blocks in bucket pass
constexpr int PPT  = 16;              // points/thread/chunk
constexpr int CHUNK = 256 * PPT;      // 4096
constexpr int NBKT = 100;             // 10x10 tiles of 25x25 cells
constexpr int NCELL = 625;            // cells per bucket
constexpr int CAPB = 43008;           // records capacity per bucket
constexpr int NSL  = 8;               // bnstats slices per channel
constexpr int NSPL = 4;               // reduce split factor

__device__ __forceinline__ unsigned f2ord(float f) {
    unsigned u = __float_as_uint(f);
    return (u & 0x80000000u) ? ~u : (u | 0x80000000u);
}
__device__ __forceinline__ float ord2f(unsigned u) {
    unsigned b = (u & 0x80000000u) ? (u & 0x7FFFFFFFu) : ~u;
    return __uint_as_float(b);
}

// ---- prep: zero gcnt + all three weight transposes in one launch ---------
// wt layout: [ic][tap][oc]
__global__ void k_prep(const float* __restrict__ w1, float* __restrict__ wt1,
                       const float* __restrict__ w2, float* __restrict__ wt2,
                       const float* __restrict__ w3, float* __restrict__ wt3,
                       unsigned* __restrict__ gcnt) {
    int i = blockIdx.x * blockDim.x + threadIdx.x;
    if (i < 128) gcnt[i] = 0u;
    constexpr int N1 = 32 * 4 * 9;     // 1152
    constexpr int N2 = 64 * 32 * 9;    // 18432
    constexpr int N3 = 64 * 64 * 9;    // 36864
    if (i < N1) {
        int oc = i / 36, r = i % 36, ic = r / 9, k = r % 9;
        wt1[(ic * 9 + k) * 32 + oc] = w1[i];
    } else if (i < N1 + N2) {
        int e = i - N1;
        int oc = e / 288, r = e % 288, ic = r / 9, k = r % 9;
        wt2[(ic * 9 + k) * 64 + oc] = w2[e];
    } else if (i < N1 + N2 + N3) {
        int e = i - N1 - N2;
        int oc = e / 576, r = e % 576, ic = r / 9, k = r % 9;
        wt3[(ic * 9 + k) * 64 + oc] = w3[e];
    }
}

// ---- pass B: bin points into bucket record arrays (r12 verbatim) ---------
// rec = z_ord(32) | cell_local(10) | inten_q22(22)
__launch_bounds__(256)
__global__ void k_bucket(const float4* __restrict__ pts, int n,
                         unsigned long long* __restrict__ recs,
                         unsigned* __restrict__ gcnt) {
    __shared__ unsigned lcnt[NBKT];
    __shared__ unsigned lbase[NBKT];
    const int tid = threadIdx.x;
    if (tid < NBKT) lcnt[tid] = 0u;
    __syncthreads();

    const int ppb = (n + NB - 1) / NB;
    const int start = blockIdx.x * ppb;
    const int end = min(start + ppb, n);

    for (int c0 = start; c0 < end; c0 += CHUNK) {
        unsigned long long rec[PPT];
        int bkt[PPT];
        unsigned slot[PPT];
        unsigned vmask = 0u;
#pragma unroll
        for (int k = 0; k < PPT; ++k) {
            int p = c0 + k * 256 + tid;
            if (p >= end) continue;
            float4 q = pts[p];
            if (!(q.x >= -50.0f && q.x < 50.0f && q.y >= -50.0f && q.y < 50.0f))
                continue;
            // must match JAX/np f32 semantics: f32 add, f32 div, trunc, clip
            int xi = (int)((q.x + 50.0f) / 0.4f);
            int yi = (int)((q.y + 50.0f) / 0.4f);
            xi = min(max(xi, 0), BEVW - 1);
            yi = min(max(yi, 0), BEVW - 1);
            int b  = (yi / 25) * 10 + (xi / 25);
            int cl = (yi % 25) * 25 + (xi % 25);
            unsigned iq = (unsigned)(q.w * 4194304.0f);   // 2^22, q.w in [0,1)
            rec[k] = ((unsigned long long)f2ord(q.z) << 32) |
                     ((unsigned long long)(unsigned)cl << 22) | iq;
            bkt[k] = b;
            slot[k] = atomicAdd(&lcnt[b], 1u);
            vmask |= 1u << k;
        }
        __syncthreads();
        if (tid < NBKT) {
            unsigned c = lcnt[tid];
            if (c) lbase[tid] = atomicAdd(&gcnt[tid], c);
            lcnt[tid] = 0u;
        }
        __syncthreads();
#pragma unroll
        for (int k = 0; k < PPT; ++k) {
            if (!((vmask >> k) & 1u)) continue;
            unsigned idx = lbase[bkt[k]] + slot[k];
            if (idx < (unsigned)CAPB)
                recs[(size_t)bkt[k] * CAPB + idx] = rec[k];
        }
    }
}

// ---- pass C (fallback): per-bucket LDS reduction + fused finalize --------
__launch_bounds__(1024)
__global__ void k_reduce(const unsigned long long* __restrict__ recs,
                         const unsigned* __restrict__ gcnt,
                         float* __restrict__ bev) {
    __shared__ unsigned mxA[NCELL], mnA[NCELL], ctA[NCELL], siA[NCELL];
    const int b = blockIdx.x;
    for (int i = threadIdx.x; i < NCELL; i += 1024) {
        mxA[i] = 0u; mnA[i] = 0xFFFFFFFFu; ctA[i] = 0u; siA[i] = 0u;
    }
    __syncthreads();
    const unsigned nb = min(gcnt[b], (unsigned)CAPB);
    const unsigned long long* rb = recs + (size_t)b * CAPB;
    for (unsigned i = threadIdx.x; i < nb; i += 1024) {
        unsigned long long r = rb[i];
        unsigned zo = (unsigned)(r >> 32);
        unsigned cl = ((unsigned)(r >> 22)) & 0x3FFu;
        unsigned iq = (unsigned)r & 0x3FFFFFu;
        atomicMax(&mxA[cl], zo);
        atomicMin(&mnA[cl], zo);
        atomicAdd(&ctA[cl], 1u);
        atomicAdd(&siA[cl], iq);
    }
    __syncthreads();
    const int tx = b % 10, ty = b / 10;
    for (int i = threadIdx.x; i < NCELL; i += 1024) {
        int cy = ty * 25 + i / 25, cx = tx * 25 + i % 25;
        int cell = cy * BEVW + cx;
        unsigned c = ctA[i];
        bool has = c > 0u;
        float dn = (float)c;
        float isum = (float)siA[i] * (1.0f / 4194304.0f);
        bev[0 * SZC + cell] = has ? ord2f(mxA[i]) : 0.0f;
        bev[1 * SZC + cell] = has ? ord2f(mnA[i]) : 0.0f;
        bev[2 * SZC + cell] = log1pf(dn);
        bev[3 * SZC + cell] = has ? isum / dn : 0.0f;
    }
}

// ---- pass C (split): partial reduce over a quarter of a bucket -----------
__launch_bounds__(1024)
__global__ void k_reduceP(const unsigned long long* __restrict__ recs,
                          const unsigned* __restrict__ gcnt,
                          uint4* __restrict__ parts) {
    __shared__ unsigned mxA[NCELL], mnA[NCELL], ctA[NCELL], siA[NCELL];
    const int b = blockIdx.x, s = blockIdx.y;
    for (int i = threadIdx.x; i < NCELL; i += 1024) {
        mxA[i] = 0u; mnA[i] = 0xFFFFFFFFu; ctA[i] = 0u; siA[i] = 0u;
    }
    __syncthreads();
    const unsigned nb = min(gcnt[b], (unsigned)CAPB);
    const unsigned lo = nb * (unsigned)s / NSPL;
    const unsigned hi = nb * (unsigned)(s + 1) / NSPL;
    const unsigned long long* rb = recs + (size_t)b * CAPB;
    for (unsigned i = lo + threadIdx.x; i < hi; i += 1024) {
        unsigned long long r = rb[i];
        unsigned zo = (unsigned)(r >> 32);
        unsigned cl = ((unsigned)(r >> 22)) & 0x3FFu;
        unsigned iq = (unsigned)r & 0x3FFFFFu;
        atomicMax(&mxA[cl], zo);
        atomicMin(&mnA[cl], zo);
        atomicAdd(&ctA[cl], 1u);
        atomicAdd(&siA[cl], iq);
    }
    __syncthreads();
    uint4* dst = parts + ((size_t)b * NSPL + s) * NCELL;
    for (int i = threadIdx.x; i < NCELL; i += 1024)
        dst[i] = make_uint4(mxA[i], mnA[i], ctA[i], siA[i]);
}

// ---- merge partials (fixed order) + finalize BEV -------------------------
__global__ void k_merge(const uint4* __restrict__ parts, float* __restrict__ bev) {
    int t = blockIdx.x * blockDim.x + threadIdx.x;
    if (t >= NBKT * NCELL) return;
    const int b = t / NCELL, i = t % NCELL;
    unsigned mx = 0u, mn = 0xFFFFFFFFu, ct = 0u, si = 0u;
#pragma unroll
    for (int s = 0; s < NSPL; ++s) {
        uint4 p = parts[((size_t)b * NSPL + s) * NCELL + i];
        mx = max(mx, p.x);
        mn = min(mn, p.y);
        ct += p.z;
        si += p.w;
    }
    const int tx = b % 10, ty = b / 10;
    int cy = ty * 25 + i / 25, cx = tx * 25 + i % 25;
    int cell = cy * BEVW + cx;
    bool has = ct > 0u;
    float dn = (float)ct;
    float isum = (float)si * (1.0f / 4194304.0f);
    bev[0 * SZC + cell] = has ? ord2f(mx) : 0.0f;
    bev[1 * SZC + cell] = has ? ord2f(mn) : 0.0f;
    bev[2 * SZC + cell] = log1pf(dn);
    bev[3 * SZC + cell] = has ? isum / dn : 0.0f;
}

// ---- conv 3x3 SAME, 16x16 tile, 1 px/thread, SGPR weights (r18 body) -----
// FUSE: per-block fold of f64 BN partials (part,g,beta) -> LDS sAB, then
// staging applies relu(A*x+B). Fold is fixed-order f64 -> bitwise-identical
// across blocks (matches old bnstats2 exactly).
template <int CIN, int COUT, int ICB, int OCG, bool FUSE>
__launch_bounds__(256)
__global__ void k_conv(const float* __restrict__ in, const float* __restrict__ wt,
                       const float* __restrict__ bias,
                       const double* __restrict__ part, const float* __restrict__ g,
                       const float* __restrict__ beta,
                       float* __restrict__ out) {
    constexpr int RS = 24;                    // padded row stride
    __shared__ float s_in[ICB][18 * RS];
    __shared__ float sAB[2 * CIN];

    const int tid = threadIdx.x;
    const int u = tid & 15, v = tid >> 4;
    const int tile = blockIdx.x;              // 0..255
    const int tx = (tile & 15) * 16, ty = (tile >> 4) * 16;
    const int oc0 = blockIdx.y * OCG;
    const bool interior = (tx >= 16) && (tx <= 224) && (ty >= 16) && (ty <= 224);

    if (FUSE) {
        for (int c = tid; c < CIN; c += 256) {
            double S = 0.0, S2 = 0.0;
            for (int s = 0; s < NSL; ++s) {
                S  += part[(c * NSL + s) * 2];
                S2 += part[(c * NSL + s) * 2 + 1];
            }
            double mu  = S / (double)SZC;
            double var = S2 / (double)SZC - mu * mu;
            double A = (1.0 / sqrt(var + 1e-5)) * (double)g[c];
            sAB[2 * c]     = (float)A;
            sAB[2 * c + 1] = (float)((double)beta[c] - mu * A);
        }
    }
    // visibility: first phase's __syncthreads below covers sAB writes

    float acc[OCG];
#pragma unroll
    for (int o = 0; o < OCG; ++o) acc[o] = 0.0f;

    for (int ic0 = 0; ic0 < CIN; ic0 += ICB) {
        __syncthreads();
        if (interior) {
            const float* base = in + (size_t)ic0 * SZC + (ty - 1) * BEVW + (tx - 1);
            for (int e = tid; e < ICB * 144; e += 256) {
                int c = e / 144, rr = e % 144;
                int r = rr >> 3, pp = rr & 7;
                int q = 1 + 2 * pp;
                float2 x2 = *(const float2*)(base + (size_t)c * SZC + r * BEVW + q);
                if (FUSE) {
                    int cg = ic0 + c;
                    float A = sAB[2 * cg], Bc = sAB[2 * cg + 1];
                    x2.x = fmaxf(fmaf(x2.x, A, Bc), 0.0f);
                    x2.y = fmaxf(fmaf(x2.y, A, Bc), 0.0f);
                }
                *(float2*)&s_in[c][r * RS + q + 1] = x2;
            }
            for (int e = tid; e < ICB * 36; e += 256) {
                int c = e / 36, t = e % 36;
                int r = t >> 1, q = (t & 1) ? 17 : 0;
                float x = base[(size_t)c * SZC + r * BEVW + q];
                if (FUSE) {
                    int cg = ic0 + c;
                    x = fmaxf(fmaf(x, sAB[2 * cg], sAB[2 * cg + 1]), 0.0f);
                }
                s_in[c][r * RS + q + 1] = x;
            }
        } else {
            for (int e = tid; e < ICB * 324; e += 256) {
                int c = e / 324, rem = e % 324;
                int r = rem / 18, q = rem % 18;
                int cg = ic0 + c;
                int gy = ty - 1 + r, gx = tx - 1 + q;
                float x = 0.0f;
                if (gy >= 0 && gy < BEVW && gx >= 0 && gx < BEVW) {
                    x = in[(size_t)cg * SZC + gy * BEVW + gx];
                    if (FUSE) x = fmaxf(fmaf(x, sAB[2 * cg], sAB[2 * cg + 1]), 0.0f);
                }
                s_in[c][r * RS + q + 1] = x;
            }
        }
        __syncthreads();

#pragma unroll
        for (int icl = 0; icl < ICB; ++icl) {
            const int icg = ic0 + icl;
#pragma unroll
            for (int tap = 0; tap < 9; ++tap) {
                const int ky = tap / 3, kx = tap % 3;
                float x = s_in[icl][(v + ky) * RS + (u + kx) + 1];
                // block-uniform address -> scalar loads into SGPRs
                const float* wk = wt + ((size_t)(icg * 9 + tap) * COUT + oc0);
#pragma unroll
                for (int o = 0; o < OCG; ++o)
                    acc[o] = fmaf(x, wk[o], acc[o]);
            }
        }
    }

    const int ox = tx + u, oy = ty + v;
    if (ox < BEVW && oy < BEVW) {
#pragma unroll
        for (int o = 0; o < OCG; ++o)
            out[(size_t)(oc0 + o) * SZC + oy * BEVW + ox] = acc[o] + bias[oc0 + o];
    }
}

// ---- BN stats stage 1: per (channel, slice) f64 partials -----------------
__global__ void k_bnstats1(const float* __restrict__ y, double* __restrict__ part) {
    const int c = blockIdx.x, s = blockIdx.y;
    const int lo = s * ((SZC + NSL - 1) / NSL);
    const int hi = min(lo + (SZC + NSL - 1) / NSL, SZC);
    const float* p = y + (size_t)c * SZC;
    double sm = 0.0, s2 = 0.0;
    for (int i = lo + threadIdx.x; i < hi; i += 256) {
        float v = p[i];
        sm += (double)v;
        s2 += (double)v * (double)v;
    }
    for (int off = 32; off; off >>= 1) {
        sm += __shfl_down(sm, off);
        s2 += __shfl_down(s2, off);
    }
    __shared__ double sh[8];
    int wid = threadIdx.x >> 6;
    if ((threadIdx.x & 63) == 0) { sh[wid * 2] = sm; sh[wid * 2 + 1] = s2; }
    __syncthreads();
    if (threadIdx.x == 0) {
        double S = 0.0, S2 = 0.0;
        for (int wv = 0; wv < 4; ++wv) { S += sh[wv * 2]; S2 += sh[wv * 2 + 1]; }
        part[(c * NSL + s) * 2]     = S;
        part[(c * NSL + s) * 2 + 1] = S2;
    }
}

// ---- final BN apply + ReLU (folds own channel's partials) ----------------
__global__ void k_bnreluS(const float* __restrict__ y, const double* __restrict__ part,
                          const float* __restrict__ g, const float* __restrict__ beta,
                          float* __restrict__ out) {
    int c = blockIdx.y;
    int i = blockIdx.x * blockDim.x + threadIdx.x;
    if (i >= SZC) return;
    double S = 0.0, S2 = 0.0;
    for (int s = 0; s < NSL; ++s) {
        S  += part[(c * NSL + s) * 2];
        S2 += part[(c * NSL + s) * 2 + 1];
    }
    double mu  = S / (double)SZC;
    double var = S2 / (double)SZC - mu * mu;
    double Ad = (1.0 / sqrt(var + 1e-5)) * (double)g[c];
    float A = (float)Ad;
    float B = (float)((double)beta[c] - mu * Ad);
    size_t idx = (size_t)c * SZC + i;
    out[idx] = fmaxf(fmaf(y[idx], A, B), 0.0f);
}

// ---------------------------------------------------------------------------
extern "C" void kernel_launch(void* const* d_in, const int* in_sizes, int n_in,
                              void* d_out, int out_size, void* d_ws, size_t ws_size,
                              hipStream_t stream) {
    const float4* pts = (const float4*)d_in[0];
    const float* w1 = (const float*)d_in[1];
    const float* b1 = (const float*)d_in[2];
    const float* g1 = (const float*)d_in[3];
    const float* be1 = (const float*)d_in[4];
    const float* w2 = (const float*)d_in[5];
    const float* b2 = (const float*)d_in[6];
    const float* g2 = (const float*)d_in[7];
    const float* be2 = (const float*)d_in[8];
    const float* w3 = (const float*)d_in[9];
    const float* b3 = (const float*)d_in[10];
    const float* g3 = (const float*)d_in[11];
    const float* be3 = (const float*)d_in[12];

    float* ws = (float*)d_ws;
    const size_t wsf = ws_size / 4;

    // --- fixed tail at end of workspace ---
    constexpr size_t TAILF = 128 + 250000 + 64 + 128 + 128 + 2048 + 1152 + 18432 + 36864;
    float* tail = ws + (wsf - TAILF);
    unsigned* gcnt = (unsigned*)tail;
    float* bev = tail + 128;                  // 4*SZC
    float* st1 = bev + 4 * SZC;               // 64  (unused, layout keep)
    float* st2 = st1 + 64;                    // 128
    float* st3 = st2 + 128;                   // 128
    double* part = (double*)(st3 + 128);      // 64*NSL*2 doubles = 2048 floats
    float* wt1 = st3 + 128 + 2048;            // 1152
    float* wt2 = wt1 + 1152;                  // 18432
    float* wt3 = wt2 + 18432;                 // 36864
    (void)st1; (void)st2; (void)st3;

    // --- dynamic region: recs, then activations alias (recs dead) ---
    unsigned long long* recs = (unsigned long long*)ws;   // 8,601,600 floats
    constexpr size_t RECS_F = (size_t)NBKT * CAPB * 2;    // 8,601,600
    float* y1 = ws;                                       // 32*SZC
    float* y2 = ws + 2000000;                             // 64*SZC
    float* out = (float*)d_out;

    // split-reduce partials: 100*4*625 uint4 = 1,000,000 floats, after recs
    constexpr size_t PARTS_F = (size_t)NBKT * NSPL * NCELL * 4;
    const bool splitR = wsf >= RECS_F + PARTS_F + TAILF + 1024;
    uint4* partsR = (uint4*)(ws + RECS_F);

    int n = in_sizes[0] / 4;                              // 5,000,000 points
    const int cellBlocks = (SZC + 255) / 256;

    // prep: gcnt zero + all weight transposes (one launch)
    k_prep<<<(56448 + 255) / 256, 256, 0, stream>>>(w1, wt1, w2, wt2, w3, wt3, gcnt);

    // points -> BEV
    k_bucket<<<NB, 256, 0, stream>>>(pts, n, recs, gcnt);
    if (splitR) {
        k_reduceP<<<dim3(NBKT, NSPL), 1024, 0, stream>>>(recs, gcnt, partsR);
        k_merge<<<(NBKT * NCELL + 255) / 256, 256, 0, stream>>>(partsR, bev);
    } else {
        k_reduce<<<NBKT, 1024, 0, stream>>>(recs, gcnt, bev);
    }

    // layer 1: 4 -> 32 (raw conv out; BN1+ReLU consumed by conv2 staging)
    k_conv<4, 32, 4, 16, false><<<dim3(256, 2), 256, 0, stream>>>(
        bev, wt1, b1, nullptr, nullptr, nullptr, y1);
    k_bnstats1<<<dim3(32, NSL), 256, 0, stream>>>(y1, part);

    // layer 2: 32 -> 64 (folds part+g1+be1 -> sAB in-kernel)
    k_conv<32, 64, 8, 16, true><<<dim3(256, 4), 256, 0, stream>>>(
        y1, wt2, b2, part, g1, be1, y2);
    k_bnstats1<<<dim3(64, NSL), 256, 0, stream>>>(y2, part);

    // layer 3: 64 -> 64 (folds part+g2+be2; raw out -> d_out)
    k_conv<64, 64, 8, 16, true><<<dim3(256, 4), 256, 0, stream>>>(
        y2, wt3, b3, part, g2, be2, out);
    k_bnstats1<<<dim3(64, NSL), 256, 0, stream>>>(out, part);

    // final BN3 + ReLU in place (folds own channel)
    k_bnreluS<<<dim3(cellBlocks, 64), 256, 0, stream>>>(out, part, g3, be3, out);
}

// Round 20
// 277.035 us; speedup vs baseline: 1.0964x; 1.0002x over previous
//
#include <hip/hip_runtime.h>

// ---------------------------------------------------------------------------
// BEV encoder: bucketed points->BEV (LDS-aggregated) + 3x conv-BN-ReLU
// v17 = r19 (champion: 277.1us) + power-of-2 bucket geometry:
//   16x16 grid of 16x16-cell buckets -> bucket/cell indices via shifts/ands,
//   eliminating 4 div/mod-by-25 magic sequences (~10 VALU instrs/point) in
//   the VALU-issue-bound k_bucket (measured ~18 instrs/point).
// Same record set per cell, commutative u32 reduce, fixed merge order ->
// bit-identical output. Conv/BN chain = r19 exact (converged).
// ---------------------------------------------------------------------------

constexpr int BEVW = 250;
constexpr int SZC  = BEVW * BEVW;     // 62500 cells
constexpr int NB   = 512;             // blocks in bucket pass
constexpr int PPT  = 16;              // points/thread/chunk
constexpr int CHUNK = 256 * PPT;      // 4096
constexpr int NBKT = 256;             // 16x16 tiles of 16x16 cells
constexpr int NCELL = 256;            // cells per bucket
constexpr int CAPB = 18432;           // records/bucket (E=16.9k, +11 sigma)
constexpr int NSL  = 8;               // bnstats slices per channel
constexpr int NSPL = 2;               // reduce split factor

__device__ __forceinline__ unsigned f2ord(float f) {
    unsigned u = __float_as_uint(f);
    return (u & 0x80000000u) ? ~u : (u | 0x80000000u);
}
__device__ __forceinline__ float ord2f(unsigned u) {
    unsigned b = (u & 0x80000000u) ? (u & 0x7FFFFFFFu) : ~u;
    return __uint_as_float(b);
}

// ---- prep: zero gcnt + all three weight transposes in one launch ---------
__global__ void k_prep(const float* __restrict__ w1, float* __restrict__ wt1,
                       const float* __restrict__ w2, float* __restrict__ wt2,
                       const float* __restrict__ w3, float* __restrict__ wt3,
                       unsigned* __restrict__ gcnt) {
    int i = blockIdx.x * blockDim.x + threadIdx.x;
    if (i < NBKT) gcnt[i] = 0u;
    constexpr int N1 = 32 * 4 * 9;     // 1152
    constexpr int N2 = 64 * 32 * 9;    // 18432
    constexpr int N3 = 64 * 64 * 9;    // 36864
    if (i < N1) {
        int oc = i / 36, r = i % 36, ic = r / 9, k = r % 9;
        wt1[(ic * 9 + k) * 32 + oc] = w1[i];
    } else if (i < N1 + N2) {
        int e = i - N1;
        int oc = e / 288, r = e % 288, ic = r / 9, k = r % 9;
        wt2[(ic * 9 + k) * 64 + oc] = w2[e];
    } else if (i < N1 + N2 + N3) {
        int e = i - N1 - N2;
        int oc = e / 576, r = e % 576, ic = r / 9, k = r % 9;
        wt3[(ic * 9 + k) * 64 + oc] = w3[e];
    }
}

// ---- pass B: bin points into bucket record arrays ------------------------
// rec = z_ord(32) | cell_local(10) | inten_q22(22); bucket/cell via shifts.
__launch_bounds__(256)
__global__ void k_bucket(const float4* __restrict__ pts, int n,
                         unsigned long long* __restrict__ recs,
                         unsigned* __restrict__ gcnt) {
    __shared__ unsigned lcnt[NBKT];
    __shared__ unsigned lbase[NBKT];
    const int tid = threadIdx.x;
    lcnt[tid] = 0u;                    // NBKT == blockDim.x == 256
    __syncthreads();

    const int ppb = (n + NB - 1) / NB;
    const int start = blockIdx.x * ppb;
    const int end = min(start + ppb, n);

    for (int c0 = start; c0 < end; c0 += CHUNK) {
        unsigned long long rec[PPT];
        int bkt[PPT];
        unsigned slot[PPT];
        unsigned vmask = 0u;
#pragma unroll
        for (int k = 0; k < PPT; ++k) {
            int p = c0 + k * 256 + tid;
            if (p >= end) continue;
            float4 q = pts[p];
            if (!(q.x >= -50.0f && q.x < 50.0f && q.y >= -50.0f && q.y < 50.0f))
                continue;
            // must match JAX/np f32 semantics: f32 add, f32 div (exact IEEE,
            // do NOT use *2.5f), trunc, clip
            int xi = (int)((q.x + 50.0f) / 0.4f);
            int yi = (int)((q.y + 50.0f) / 0.4f);
            xi = min(max(xi, 0), BEVW - 1);
            yi = min(max(yi, 0), BEVW - 1);
            int b  = (yi & 0xF0) | (xi >> 4);           // (yi/16)*16 + xi/16
            int cl = ((yi & 15) << 4) | (xi & 15);      // (yi%16)*16 + xi%16
            unsigned iq = (unsigned)(q.w * 4194304.0f); // 2^22, q.w in [0,1)
            rec[k] = ((unsigned long long)f2ord(q.z) << 32) |
                     ((unsigned long long)(unsigned)cl << 22) | iq;
            bkt[k] = b;
            slot[k] = atomicAdd(&lcnt[b], 1u);
            vmask |= 1u << k;
        }
        __syncthreads();
        {
            unsigned c = lcnt[tid];
            if (c) lbase[tid] = atomicAdd(&gcnt[tid], c);
            lcnt[tid] = 0u;
        }
        __syncthreads();
#pragma unroll
        for (int k = 0; k < PPT; ++k) {
            if (!((vmask >> k) & 1u)) continue;
            unsigned idx = lbase[bkt[k]] + slot[k];
            if (idx < (unsigned)CAPB)
                recs[(size_t)bkt[k] * CAPB + idx] = rec[k];
        }
    }
}

// ---- pass C (fallback): per-bucket LDS reduction + fused finalize --------
__launch_bounds__(1024)
__global__ void k_reduce(const unsigned long long* __restrict__ recs,
                         const unsigned* __restrict__ gcnt,
                         float* __restrict__ bev) {
    __shared__ unsigned mxA[NCELL], mnA[NCELL], ctA[NCELL], siA[NCELL];
    const int b = blockIdx.x;
    for (int i = threadIdx.x; i < NCELL; i += 1024) {
        mxA[i] = 0u; mnA[i] = 0xFFFFFFFFu; ctA[i] = 0u; siA[i] = 0u;
    }
    __syncthreads();
    const unsigned nb = min(gcnt[b], (unsigned)CAPB);
    const unsigned long long* rb = recs + (size_t)b * CAPB;
    for (unsigned i = threadIdx.x; i < nb; i += 1024) {
        unsigned long long r = rb[i];
        unsigned zo = (unsigned)(r >> 32);
        unsigned cl = ((unsigned)(r >> 22)) & 0x3FFu;
        unsigned iq = (unsigned)r & 0x3FFFFFu;
        atomicMax(&mxA[cl], zo);
        atomicMin(&mnA[cl], zo);
        atomicAdd(&ctA[cl], 1u);
        atomicAdd(&siA[cl], iq);
    }
    __syncthreads();
    const int bx = b & 15, by = b >> 4;
    for (int i = threadIdx.x; i < NCELL; i += 1024) {
        int cy = by * 16 + (i >> 4), cx = bx * 16 + (i & 15);
        if (cy >= BEVW || cx >= BEVW) continue;   // edge buckets overhang
        int cell = cy * BEVW + cx;
        unsigned c = ctA[i];
        bool has = c > 0u;
        float dn = (float)c;
        float isum = (float)siA[i] * (1.0f / 4194304.0f);
        bev[0 * SZC + cell] = has ? ord2f(mxA[i]) : 0.0f;
        bev[1 * SZC + cell] = has ? ord2f(mnA[i]) : 0.0f;
        bev[2 * SZC + cell] = log1pf(dn);
        bev[3 * SZC + cell] = has ? isum / dn : 0.0f;
    }
}

// ---- pass C (split): partial reduce over a half of a bucket --------------
__launch_bounds__(1024)
__global__ void k_reduceP(const unsigned long long* __restrict__ recs,
                          const unsigned* __restrict__ gcnt,
                          uint4* __restrict__ parts) {
    __shared__ unsigned mxA[NCELL], mnA[NCELL], ctA[NCELL], siA[NCELL];
    const int b = blockIdx.x, s = blockIdx.y;
    for (int i = threadIdx.x; i < NCELL; i += 1024) {
        mxA[i] = 0u; mnA[i] = 0xFFFFFFFFu; ctA[i] = 0u; siA[i] = 0u;
    }
    __syncthreads();
    const unsigned nb = min(gcnt[b], (unsigned)CAPB);
    const unsigned lo = nb * (unsigned)s / NSPL;
    const unsigned hi = nb * (unsigned)(s + 1) / NSPL;
    const unsigned long long* rb = recs + (size_t)b * CAPB;
    for (unsigned i = lo + threadIdx.x; i < hi; i += 1024) {
        unsigned long long r = rb[i];
        unsigned zo = (unsigned)(r >> 32);
        unsigned cl = ((unsigned)(r >> 22)) & 0x3FFu;
        unsigned iq = (unsigned)r & 0x3FFFFFu;
        atomicMax(&mxA[cl], zo);
        atomicMin(&mnA[cl], zo);
        atomicAdd(&ctA[cl], 1u);
        atomicAdd(&siA[cl], iq);
    }
    __syncthreads();
    uint4* dst = parts + ((size_t)b * NSPL + s) * NCELL;
    for (int i = threadIdx.x; i < NCELL; i += 1024)
        dst[i] = make_uint4(mxA[i], mnA[i], ctA[i], siA[i]);
}

// ---- merge partials (fixed order) + finalize BEV -------------------------
__global__ void k_merge(const uint4* __restrict__ parts, float* __restrict__ bev) {
    int t = blockIdx.x * blockDim.x + threadIdx.x;
    if (t >= NBKT * NCELL) return;
    const int b = t >> 8, i = t & 255;
    const int bx = b & 15, by = b >> 4;
    int cy = by * 16 + (i >> 4), cx = bx * 16 + (i & 15);
    if (cy >= BEVW || cx >= BEVW) return;         // edge buckets overhang
    unsigned mx = 0u, mn = 0xFFFFFFFFu, ct = 0u, si = 0u;
#pragma unroll
    for (int s = 0; s < NSPL; ++s) {
        uint4 p = parts[((size_t)b * NSPL + s) * NCELL + i];
        mx = max(mx, p.x);
        mn = min(mn, p.y);
        ct += p.z;
        si += p.w;
    }
    int cell = cy * BEVW + cx;
    bool has = ct > 0u;
    float dn = (float)ct;
    float isum = (float)si * (1.0f / 4194304.0f);
    bev[0 * SZC + cell] = has ? ord2f(mx) : 0.0f;
    bev[1 * SZC + cell] = has ? ord2f(mn) : 0.0f;
    bev[2 * SZC + cell] = log1pf(dn);
    bev[3 * SZC + cell] = has ? isum / dn : 0.0f;
}

// ---- conv 3x3 SAME, 16x16 tile, 1 px/thread, SGPR weights (r19 exact) ----
template <int CIN, int COUT, int ICB, int OCG, bool FUSE>
__launch_bounds__(256)
__global__ void k_conv(const float* __restrict__ in, const float* __restrict__ wt,
                       const float* __restrict__ bias,
                       const double* __restrict__ part, const float* __restrict__ g,
                       const float* __restrict__ beta,
                       float* __restrict__ out) {
    constexpr int RS = 24;                    // padded row stride
    __shared__ float s_in[ICB][18 * RS];
    __shared__ float sAB[2 * CIN];

    const int tid = threadIdx.x;
    const int u = tid & 15, v = tid >> 4;
    const int tile = blockIdx.x;              // 0..255
    const int tx = (tile & 15) * 16, ty = (tile >> 4) * 16;
    const int oc0 = blockIdx.y * OCG;
    const bool interior = (tx >= 16) && (tx <= 224) && (ty >= 16) && (ty <= 224);

    if (FUSE) {
        for (int c = tid; c < CIN; c += 256) {
            double S = 0.0, S2 = 0.0;
            for (int s = 0; s < NSL; ++s) {
                S  += part[(c * NSL + s) * 2];
                S2 += part[(c * NSL + s) * 2 + 1];
            }
            double mu  = S / (double)SZC;
            double var = S2 / (double)SZC - mu * mu;
            double A = (1.0 / sqrt(var + 1e-5)) * (double)g[c];
            sAB[2 * c]     = (float)A;
            sAB[2 * c + 1] = (float)((double)beta[c] - mu * A);
        }
    }

    float acc[OCG];
#pragma unroll
    for (int o = 0; o < OCG; ++o) acc[o] = 0.0f;

    for (int ic0 = 0; ic0 < CIN; ic0 += ICB) {
        __syncthreads();
        if (interior) {
            const float* base = in + (size_t)ic0 * SZC + (ty - 1) * BEVW + (tx - 1);
            for (int e = tid; e < ICB * 144; e += 256) {
                int c = e / 144, rr = e % 144;
                int r = rr >> 3, pp = rr & 7;
                int q = 1 + 2 * pp;
                float2 x2 = *(const float2*)(base + (size_t)c * SZC + r * BEVW + q);
                if (FUSE) {
                    int cg = ic0 + c;
                    float A = sAB[2 * cg], Bc = sAB[2 * cg + 1];
                    x2.x = fmaxf(fmaf(x2.x, A, Bc), 0.0f);
                    x2.y = fmaxf(fmaf(x2.y, A, Bc), 0.0f);
                }
                *(float2*)&s_in[c][r * RS + q + 1] = x2;
            }
            for (int e = tid; e < ICB * 36; e += 256) {
                int c = e / 36, t = e % 36;
                int r = t >> 1, q = (t & 1) ? 17 : 0;
                float x = base[(size_t)c * SZC + r * BEVW + q];
                if (FUSE) {
                    int cg = ic0 + c;
                    x = fmaxf(fmaf(x, sAB[2 * cg], sAB[2 * cg + 1]), 0.0f);
                }
                s_in[c][r * RS + q + 1] = x;
            }
        } else {
            for (int e = tid; e < ICB * 324; e += 256) {
                int c = e / 324, rem = e % 324;
                int r = rem / 18, q = rem % 18;
                int cg = ic0 + c;
                int gy = ty - 1 + r, gx = tx - 1 + q;
                float x = 0.0f;
                if (gy >= 0 && gy < BEVW && gx >= 0 && gx < BEVW) {
                    x = in[(size_t)cg * SZC + gy * BEVW + gx];
                    if (FUSE) x = fmaxf(fmaf(x, sAB[2 * cg], sAB[2 * cg + 1]), 0.0f);
                }
                s_in[c][r * RS + q + 1] = x;
            }
        }
        __syncthreads();

#pragma unroll
        for (int icl = 0; icl < ICB; ++icl) {
            const int icg = ic0 + icl;
#pragma unroll
            for (int tap = 0; tap < 9; ++tap) {
                const int ky = tap / 3, kx = tap % 3;
                float x = s_in[icl][(v + ky) * RS + (u + kx) + 1];
                // block-uniform address -> scalar loads into SGPRs
                const float* wk = wt + ((size_t)(icg * 9 + tap) * COUT + oc0);
#pragma unroll
                for (int o = 0; o < OCG; ++o)
                    acc[o] = fmaf(x, wk[o], acc[o]);
            }
        }
    }

    const int ox = tx + u, oy = ty + v;
    if (ox < BEVW && oy < BEVW) {
#pragma unroll
        for (int o = 0; o < OCG; ++o)
            out[(size_t)(oc0 + o) * SZC + oy * BEVW + ox] = acc[o] + bias[oc0 + o];
    }
}

// ---- BN stats stage 1: per (channel, slice) f64 partials -----------------
__global__ void k_bnstats1(const float* __restrict__ y, double* __restrict__ part) {
    const int c = blockIdx.x, s = blockIdx.y;
    const int lo = s * ((SZC + NSL - 1) / NSL);
    const int hi = min(lo + (SZC + NSL - 1) / NSL, SZC);
    const float* p = y + (size_t)c * SZC;
    double sm = 0.0, s2 = 0.0;
    for (int i = lo + threadIdx.x; i < hi; i += 256) {
        float v = p[i];
        sm += (double)v;
        s2 += (double)v * (double)v;
    }
    for (int off = 32; off; off >>= 1) {
        sm += __shfl_down(sm, off);
        s2 += __shfl_down(s2, off);
    }
    __shared__ double sh[8];
    int wid = threadIdx.x >> 6;
    if ((threadIdx.x & 63) == 0) { sh[wid * 2] = sm; sh[wid * 2 + 1] = s2; }
    __syncthreads();
    if (threadIdx.x == 0) {
        double S = 0.0, S2 = 0.0;
        for (int wv = 0; wv < 4; ++wv) { S += sh[wv * 2]; S2 += sh[wv * 2 + 1]; }
        part[(c * NSL + s) * 2]     = S;
        part[(c * NSL + s) * 2 + 1] = S2;
    }
}

// ---- final BN apply + ReLU (folds own channel's partials) ----------------
__global__ void k_bnreluS(const float* __restrict__ y, const double* __restrict__ part,
                          const float* __restrict__ g, const float* __restrict__ beta,
                          float* __restrict__ out) {
    int c = blockIdx.y;
    int i = blockIdx.x * blockDim.x + threadIdx.x;
    if (i >= SZC) return;
    double S = 0.0, S2 = 0.0;
    for (int s = 0; s < NSL; ++s) {
        S  += part[(c * NSL + s) * 2];
        S2 += part[(c * NSL + s) * 2 + 1];
    }
    double mu  = S / (double)SZC;
    double var = S2 / (double)SZC - mu * mu;
    double Ad = (1.0 / sqrt(var + 1e-5)) * (double)g[c];
    float A = (float)Ad;
    float B = (float)((double)beta[c] - mu * Ad);
    size_t idx = (size_t)c * SZC + i;
    out[idx] = fmaxf(fmaf(y[idx], A, B), 0.0f);
}

// ---------------------------------------------------------------------------
extern "C" void kernel_launch(void* const* d_in, const int* in_sizes, int n_in,
                              void* d_out, int out_size, void* d_ws, size_t ws_size,
                              hipStream_t stream) {
    const float4* pts = (const float4*)d_in[0];
    const float* w1 = (const float*)d_in[1];
    const float* b1 = (const float*)d_in[2];
    const float* g1 = (const float*)d_in[3];
    const float* be1 = (const float*)d_in[4];
    const float* w2 = (const float*)d_in[5];
    const float* b2 = (const float*)d_in[6];
    const float* g2 = (const float*)d_in[7];
    const float* be2 = (const float*)d_in[8];
    const float* w3 = (const float*)d_in[9];
    const float* b3 = (const float*)d_in[10];
    const float* g3 = (const float*)d_in[11];
    const float* be3 = (const float*)d_in[12];

    float* ws = (float*)d_ws;
    const size_t wsf = ws_size / 4;

    // --- fixed tail at end of workspace ---
    constexpr size_t TAILF = 256 + 250000 + 64 + 128 + 128 + 2048 + 1152 + 18432 + 36864;
    float* tail = ws + (wsf - TAILF);
    unsigned* gcnt = (unsigned*)tail;
    float* bev = tail + 256;                  // 4*SZC
    float* pad0 = bev + 4 * SZC;              // 64+128+128 (layout keep)
    double* part = (double*)(pad0 + 320);     // 64*NSL*2 doubles = 2048 floats
    float* wt1 = pad0 + 320 + 2048;           // 1152
    float* wt2 = wt1 + 1152;                  // 18432
    float* wt3 = wt2 + 18432;                 // 36864
    (void)pad0;

    // --- dynamic region: recs, then activations alias (recs dead) ---
    unsigned long long* recs = (unsigned long long*)ws;   // 256*18432 u64
    constexpr size_t RECS_F = (size_t)NBKT * CAPB * 2;    // 9,437,184 floats
    float* y1 = ws;                                       // 32*SZC
    float* y2 = ws + 2000000;                             // 64*SZC
    float* out = (float*)d_out;

    // split-reduce partials: 256*2*256 uint4 = 524,288 floats, after recs
    constexpr size_t PARTS_F = (size_t)NBKT * NSPL * NCELL * 4;
    const bool splitR = wsf >= RECS_F + PARTS_F + TAILF + 1024;
    uint4* partsR = (uint4*)(ws + RECS_F);

    int n = in_sizes[0] / 4;                              // 5,000,000 points
    const int cellBlocks = (SZC + 255) / 256;

    // prep: gcnt zero + all weight transposes (one launch)
    k_prep<<<(56448 + 255) / 256, 256, 0, stream>>>(w1, wt1, w2, wt2, w3, wt3, gcnt);

    // points -> BEV
    k_bucket<<<NB, 256, 0, stream>>>(pts, n, recs, gcnt);
    if (splitR) {
        k_reduceP<<<dim3(NBKT, NSPL), 1024, 0, stream>>>(recs, gcnt, partsR);
        k_merge<<<(NBKT * NCELL + 255) / 256, 256, 0, stream>>>(partsR, bev);
    } else {
        k_reduce<<<NBKT, 1024, 0, stream>>>(recs, gcnt, bev);
    }

    // layer 1: 4 -> 32 (raw conv out; BN1+ReLU consumed by conv2 staging)
    k_conv<4, 32, 4, 16, false><<<dim3(256, 2), 256, 0, stream>>>(
        bev, wt1, b1, nullptr, nullptr, nullptr, y1);
    k_bnstats1<<<dim3(32, NSL), 256, 0, stream>>>(y1, part);

    // layer 2: 32 -> 64 (folds part+g1+be1 -> sAB in-kernel)
    k_conv<32, 64, 8, 16, true><<<dim3(256, 4), 256, 0, stream>>>(
        y1, wt2, b2, part, g1, be1, y2);
    k_bnstats1<<<dim3(64, NSL), 256, 0, stream>>>(y2, part);

    // layer 3: 64 -> 64 (folds part+g2+be2; raw out -> d_out)
    k_conv<64, 64, 8, 16, true><<<dim3(256, 4), 256, 0, stream>>>(
        y2, wt3, b3, part, g2, be2, out);
    k_bnstats1<<<dim3(64, NSL), 256, 0, stream>>>(out, part);

    // final BN3 + ReLU in place (folds own channel)
    k_bnreluS<<<dim3(cellBlocks, 64), 256, 0, stream>>>(out, part, g3, be3, out);
}